// Round 3
// baseline (1431.311 us; speedup 1.0000x reference)
//
#include <hip/hip_runtime.h>

typedef unsigned short u16;
typedef __attribute__((ext_vector_type(8))) u16 b16x8;
typedef __attribute__((ext_vector_type(4))) float f32x4;

static constexpr int HWn = 196;   // 14*14
static constexpr int NN  = 9;     // nodes
static constexpr int Cn  = 512;   // node dim
static constexpr int CBn = 1024;  // backbone dim
static constexpr int Dn  = 128;   // lstm dim
static constexpr int BTn = 128;   // B*T

__device__ __forceinline__ float sigm(float x) { return 1.f / (1.f + expf(-x)); }

__device__ __forceinline__ u16 f2bf(float f) {
  unsigned int u = __builtin_bit_cast(unsigned int, f);
  u = (u + 0x7fff + ((u >> 16) & 1)) >> 16;  // RNE
  return (u16)u;
}

__device__ __forceinline__ float waveSum(float v) {
#pragma unroll
  for (int o = 32; o > 0; o >>= 1) v += __shfl_down(v, o, 64);
  return v;
}
__device__ __forceinline__ float waveMax(float v) {
#pragma unroll
  for (int o = 32; o > 0; o >>= 1) v = fmaxf(v, __shfl_down(v, o, 64));
  return v;
}
__device__ __forceinline__ float blockSum(float v, float* red) {
  const int lane = threadIdx.x & 63, wid = threadIdx.x >> 6;
  const int nw = blockDim.x >> 6;
  v = waveSum(v);
  __syncthreads();
  if (lane == 0) red[wid] = v;
  __syncthreads();
  float r = 0.f;
  for (int i = 0; i < nw; ++i) r += red[i];
  return r;
}
__device__ __forceinline__ float blockMax(float v, float* red) {
  const int lane = threadIdx.x & 63, wid = threadIdx.x >> 6;
  const int nw = blockDim.x >> 6;
  v = waveMax(v);
  __syncthreads();
  if (lane == 0) red[wid] = v;
  __syncthreads();
  float r = -3.4e38f;
  for (int i = 0; i < nw; ++i) r = fmaxf(r, red[i]);
  return r;
}

// ---------------- fp32 -> bf16 cast
__global__ __launch_bounds__(256) void k_cast(const float* __restrict__ in,
                                              u16* __restrict__ out, int n) {
  const int i = (blockIdx.x * 256 + threadIdx.x) * 4;
  if (i < n) {
    const float4 v = *(const float4*)&in[i];
    out[i + 0] = f2bf(v.x); out[i + 1] = f2bf(v.y);
    out[i + 2] = f2bf(v.z); out[i + 3] = f2bf(v.w);
  }
}

// ---------------- batched mid-weight cast: Wq|Wk|Wv|Wu|W_gih|W_ghh|W_ih -> contiguous bf16
__global__ __launch_bounds__(256) void k_castall(const float* __restrict__ wq,
                                                 const float* __restrict__ wk,
                                                 const float* __restrict__ wv,
                                                 const float* __restrict__ wu,
                                                 const float* __restrict__ wgih,
                                                 const float* __restrict__ wghh,
                                                 const float* __restrict__ wih,
                                                 u16* __restrict__ dst) {
  const int i = (blockIdx.x * 256 + threadIdx.x) * 4;
  if (i >= 2686976) return;
  const float* src;
  int o = i;
  if (i < 262144) { src = wq; }
  else if (i < 524288)  { src = wk;   o = i - 262144; }
  else if (i < 786432)  { src = wv;   o = i - 524288; }
  else if (i < 1048576) { src = wu;   o = i - 786432; }
  else if (i < 1835008) { src = wgih; o = i - 1048576; }
  else if (i < 2621440) { src = wghh; o = i - 1835008; }
  else                  { src = wih;  o = i - 2621440; }
  const float4 v = *(const float4*)&src[o];
  dst[i + 0] = f2bf(v.x); dst[i + 1] = f2bf(v.y);
  dst[i + 2] = f2bf(v.z); dst[i + 3] = f2bf(v.w);
}

// ---------------- x[bt][c][hw] fp32 -> xT[(bt,hw)][c] bf16
__global__ __launch_bounds__(256) void k_xt(const float* __restrict__ x,
                                            u16* __restrict__ xT) {
  __shared__ u16 T[64][201];
  const int bt = blockIdx.x, c0 = blockIdx.y * 64, tid = threadIdx.x;
  const float* xb = x + ((size_t)bt * CBn + c0) * HWn;
  for (int idx = tid; idx < 64 * HWn; idx += 256)
    T[idx / HWn][idx % HWn] = f2bf(xb[idx]);
  __syncthreads();
  unsigned int* xTu = (unsigned int*)(xT + ((size_t)bt * HWn) * CBn + c0);
  for (int idx = tid; idx < HWn * 32; idx += 256) {
    const int hw = idx >> 5, j = idx & 31;
    const unsigned int lo = T[2 * j][hw], hi = T[2 * j + 1][hw];
    xTu[(size_t)hw * (CBn / 2) + j] = lo | (hi << 16);
  }
}

// ---------------- bf16 MFMA GEMM, 128x128 tile, C[m,n] = sum_k A[m,k]*B[n,k]
// MODE 0: C fp32 row-major [M,N] (+bias if non-null)
// MODE 1: transposed epilogue: out[((m/196)*1024+n)*196 + m%196] = xres + acc + bias[n]
// MODE 3: C16 bf16 row-major = f2bf(resid[m,n] + relu(acc + bias[n]))
template <int MODE>
__global__ __launch_bounds__(256) void k_mm128(const u16* __restrict__ A,
                                               const u16* __restrict__ B,
                                               const float* __restrict__ bias,
                                               const float* __restrict__ resid,
                                               float* __restrict__ C,
                                               const int M, const int N, const int K) {
  __shared__ __align__(16) u16 As[128 * 64];
  __shared__ __align__(16) u16 Bs[128 * 64];
  const int tid = threadIdx.x;
  const int lane = tid & 63;
  const int w = tid >> 6, wr = w >> 1, wc = w & 1;
  const int m0 = blockIdx.x * 128, n0 = blockIdx.y * 128;

  // staging: 4 chunks (16B) per thread
  int srowA[4], srowB[4], slds[4], sc16[4];
#pragma unroll
  for (int i = 0; i < 4; ++i) {
    const int chunk = i * 256 + tid;
    const int row = chunk >> 3, c16 = chunk & 7;
    srowA[i] = min(m0 + row, M - 1);  // M-guard (M=144 case)
    srowB[i] = n0 + row;
    sc16[i] = c16;
    slds[i] = row * 64 + ((c16 ^ (row & 7)) << 3);  // XOR-swizzled 16B slot
  }
  uint4 ar[4], br[4];
#pragma unroll
  for (int i = 0; i < 4; ++i) {
    ar[i] = *(const uint4*)(A + (size_t)srowA[i] * K + sc16[i] * 8);
    br[i] = *(const uint4*)(B + (size_t)srowB[i] * K + sc16[i] * 8);
  }

  // fragment LDS offsets (u16 units), swizzle matched to writes
  int fa[4][2], fb[4][2];
#pragma unroll
  for (int q = 0; q < 4; ++q)
#pragma unroll
    for (int ks = 0; ks < 2; ++ks) {
      const int rowa = wr * 64 + q * 16 + (lane & 15);
      fa[q][ks] = rowa * 64 + (((ks * 4 + (lane >> 4)) ^ (rowa & 7)) << 3);
      const int rowb = wc * 64 + q * 16 + (lane & 15);
      fb[q][ks] = rowb * 64 + (((ks * 4 + (lane >> 4)) ^ (rowb & 7)) << 3);
    }

  f32x4 acc[4][4];
#pragma unroll
  for (int a = 0; a < 4; ++a)
#pragma unroll
    for (int b = 0; b < 4; ++b) acc[a][b] = f32x4{0.f, 0.f, 0.f, 0.f};

  for (int k0 = 0; k0 < K; k0 += 64) {
    __syncthreads();
#pragma unroll
    for (int i = 0; i < 4; ++i) {
      *(uint4*)&As[slds[i]] = ar[i];
      *(uint4*)&Bs[slds[i]] = br[i];
    }
    __syncthreads();
    const int kn = k0 + 64;
    if (kn < K) {
#pragma unroll
      for (int i = 0; i < 4; ++i) {
        ar[i] = *(const uint4*)(A + (size_t)srowA[i] * K + kn + sc16[i] * 8);
        br[i] = *(const uint4*)(B + (size_t)srowB[i] * K + kn + sc16[i] * 8);
      }
    }
    b16x8 af[4][2], bg[4][2];
#pragma unroll
    for (int q = 0; q < 4; ++q)
#pragma unroll
      for (int ks = 0; ks < 2; ++ks) {
        af[q][ks] = *(const b16x8*)&As[fa[q][ks]];
        bg[q][ks] = *(const b16x8*)&Bs[fb[q][ks]];
      }
#pragma unroll
    for (int ks = 0; ks < 2; ++ks)
#pragma unroll
      for (int mi = 0; mi < 4; ++mi)
#pragma unroll
        for (int nj = 0; nj < 4; ++nj) {
          if (MODE == 1)  // swapped operands -> acc holds C^T quadrant
            asm volatile("v_mfma_f32_16x16x32_bf16 %0, %1, %2, %0"
                         : "+v"(acc[mi][nj])
                         : "v"(bg[nj][ks]), "v"(af[mi][ks]));
          else
            asm volatile("v_mfma_f32_16x16x32_bf16 %0, %1, %2, %0"
                         : "+v"(acc[mi][nj])
                         : "v"(af[mi][ks]), "v"(bg[nj][ks]));
        }
  }

  if (MODE == 1) {
    // acc[mi][nj][r]: n = n0+wc*64+nj*16+(lane>>4)*4+r, m = m0+wr*64+mi*16+(lane&15)
    // stores coalesced along m (=hw within row of out[b, n, :])
#pragma unroll
    for (int nj = 0; nj < 4; ++nj) {
#pragma unroll
      for (int r = 0; r < 4; ++r) {
        const int n = n0 + wc * 64 + nj * 16 + (lane >> 4) * 4 + r;
        const float bv = bias[n];
#pragma unroll
        for (int mi = 0; mi < 4; ++mi) {
          const int m = m0 + wr * 64 + mi * 16 + (lane & 15);
          const int b = m / HWn, hw = m - b * HWn;
          const size_t adr = ((size_t)b * CBn + n) * HWn + hw;
          C[adr] = resid[adr] + acc[mi][nj][r] + bv;
        }
      }
    }
  } else {
#pragma unroll
    for (int nj = 0; nj < 4; ++nj) {
      const int n = n0 + wc * 64 + nj * 16 + (lane & 15);
      const float bv = (MODE == 3) ? bias[n] : (bias ? bias[n] : 0.f);
#pragma unroll
      for (int mi = 0; mi < 4; ++mi) {
#pragma unroll
        for (int r = 0; r < 4; ++r) {
          const int m = m0 + wr * 64 + mi * 16 + (lane >> 4) * 4 + r;
          if (m >= M) continue;
          if (MODE == 0) {
            C[(size_t)m * N + n] = acc[mi][nj][r] + bv;
          } else {  // MODE 3
            const float val = resid[(size_t)m * N + n] + fmaxf(acc[mi][nj][r] + bv, 0.f);
            ((u16*)C)[(size_t)m * N + n] = f2bf(val);
          }
        }
      }
    }
  }
}

// ---------------- attention pooling: logits -> softmax over hw -> attw
__global__ __launch_bounds__(256) void k_attnpool(const float* __restrict__ feat,
                                                  const float* __restrict__ Wattn,
                                                  float* __restrict__ attw) {
  __shared__ float S[HWn][65];
  __shared__ float Wa[NN][64];
  __shared__ float L[NN][HWn];
  __shared__ float red[4];
  const int bt = blockIdx.x, tid = threadIdx.x;
  float lacc[NN];
#pragma unroll
  for (int n = 0; n < NN; ++n) lacc[n] = 0.f;
  const float* fb = feat + (size_t)bt * HWn * Cn;
  const int srow = tid >> 4, sc4 = (tid & 15) << 2;
  for (int c0 = 0; c0 < Cn; c0 += 64) {
    for (int rr = srow; rr < HWn; rr += 16) {
      const float4 f = *(const float4*)&fb[(size_t)rr * Cn + c0 + sc4];
      S[rr][sc4] = f.x; S[rr][sc4 + 1] = f.y; S[rr][sc4 + 2] = f.z; S[rr][sc4 + 3] = f.w;
    }
    for (int idx = tid; idx < NN * 64; idx += 256)
      Wa[idx >> 6][idx & 63] = Wattn[(size_t)(idx >> 6) * Cn + c0 + (idx & 63)];
    __syncthreads();
    if (tid < HWn) {
      for (int c = 0; c < 64; ++c) {
        const float s = S[tid][c];
#pragma unroll
        for (int n = 0; n < NN; ++n) lacc[n] += Wa[n][c] * s;
      }
    }
    __syncthreads();
  }
  if (tid < HWn)
#pragma unroll
    for (int n = 0; n < NN; ++n) L[n][tid] = lacc[n];
  __syncthreads();
  for (int n = 0; n < NN; ++n) {
    const float v = (tid < HWn) ? L[n][tid] : -3.4e38f;
    const float mx = blockMax(v, red);
    const float e = (tid < HWn) ? expf(v - mx) : 0.f;
    const float s = blockSum(e, red);
    if (tid < HWn) attw[((size_t)bt * NN + n) * HWn + tid] = e / s;
  }
}

// ---------------- gf[bt,n,c] = sum_hw attw * feat
__global__ __launch_bounds__(256) void k_gf(const float* __restrict__ feat,
                                            const float* __restrict__ attw,
                                            float* __restrict__ gf) {
  __shared__ float aw[NN][HWn];
  const int bt = blockIdx.x, tid = threadIdx.x;
  for (int idx = tid; idx < NN * HWn; idx += 256)
    aw[idx / HWn][idx % HWn] = attw[(size_t)bt * NN * HWn + idx];
  __syncthreads();
  float a0[NN] = {}, a1[NN] = {};
  const float* fb = feat + (size_t)bt * HWn * Cn;
  for (int hw = 0; hw < HWn; ++hw) {
    const float f0 = fb[(size_t)hw * Cn + tid];
    const float f1 = fb[(size_t)hw * Cn + tid + 256];
#pragma unroll
    for (int n = 0; n < NN; ++n) {
      const float w = aw[n][hw];
      a0[n] += w * f0; a1[n] += w * f1;
    }
  }
#pragma unroll
  for (int n = 0; n < NN; ++n) {
    gf[((size_t)bt * NN + n) * Cn + tid] = a0[n];
    gf[((size_t)bt * NN + n) * Cn + tid + 256] = a1[n];
  }
}

// ---------------- gf2b = bf16(LN(gf @ W_gf^T + b_gf) * g1 + beta1)
__global__ __launch_bounds__(128) void k_gfln(const float* __restrict__ gf,
                                              const float* __restrict__ Wgf,
                                              const float* __restrict__ bgf,
                                              const float* __restrict__ g1,
                                              const float* __restrict__ beta1,
                                              u16* __restrict__ gf2b) {
  __shared__ __align__(16) float src[Cn];
  __shared__ float red[4];
  const int row = blockIdx.x;   // bt*9+n
  const int n = row % NN;
  const int tid = threadIdx.x;  // 128
  for (int i = tid; i < Cn; i += 128) src[i] = gf[(size_t)row * Cn + i];
  __syncthreads();
  float acc = bgf[tid];
  const float* wr = Wgf + (size_t)tid * Cn;
  for (int c = 0; c < Cn; c += 4) {
    const float4 w = *(const float4*)&wr[c];
    acc += w.x * src[c] + w.y * src[c + 1] + w.z * src[c + 2] + w.w * src[c + 3];
  }
  const float mean = blockSum(acc, red) * (1.f / 128.f);
  const float d = acc - mean;
  const float var = blockSum(d * d, red) * (1.f / 128.f);
  gf2b[(size_t)row * Dn + tid] =
      f2bf(d * rsqrtf(var + 1e-5f) * g1[n * Dn + tid] + beta1[n * Dn + tid]);
}

// ---------------- LSTM over T=8, one block per (b,n)
__global__ __launch_bounds__(256) void k_lstm(const float* __restrict__ xW,
                                              const float* __restrict__ Whh,
                                              const float* __restrict__ bhh,
                                              float* __restrict__ ys) {
  __shared__ __align__(16) float h[Dn];
  __shared__ float cc[Dn];
  __shared__ float gates[4 * Dn];
  const int blk = blockIdx.x, b = blk / NN, n = blk % NN;
  const int tid = threadIdx.x;
  if (tid < Dn) { h[tid] = 0.f; cc[tid] = 0.f; }
  __syncthreads();
  for (int t = 0; t < 8; ++t) {
    const int bt = b * 8 + t;
    const size_t xrow = ((size_t)bt * NN + n) * (4 * Dn);
#pragma unroll
    for (int gq = 0; gq < 2; ++gq) {
      const int g = tid + gq * 256;
      float acc = xW[xrow + g] + bhh[g];
      const float* wr = Whh + (size_t)g * Dn;
#pragma unroll 8
      for (int d = 0; d < Dn; d += 4) {
        const float4 w = *(const float4*)&wr[d];
        acc += w.x * h[d] + w.y * h[d + 1] + w.z * h[d + 2] + w.w * h[d + 3];
      }
      gates[g] = acc;
    }
    __syncthreads();
    if (tid < Dn) {
      const float ig = sigm(gates[tid]);
      const float fg = sigm(gates[Dn + tid]);
      const float gg = tanhf(gates[2 * Dn + tid]);
      const float og = sigm(gates[3 * Dn + tid]);
      const float cn = fg * cc[tid] + ig * gg;
      const float hn = og * tanhf(cn);
      cc[tid] = cn; h[tid] = hn;
      ys[((size_t)bt * NN + n) * Dn + tid] = hn;
    }
    __syncthreads();
  }
}

// ---------------- offsets -> khs/kws, one block per (bt,n)
__global__ __launch_bounds__(128) void k_off(const float* __restrict__ ys,
                                             const float* __restrict__ g2,
                                             const float* __restrict__ beta2,
                                             const float* __restrict__ Wpred,
                                             const float* __restrict__ bpred,
                                             const float* __restrict__ alpha,
                                             float* __restrict__ khs,
                                             float* __restrict__ kws) {
  __shared__ float red[4];
  __shared__ float cpar[4];  // ch, cw, sh, sw
  const int row = blockIdx.x;  // bt*9+n
  const int n = row % NN;
  const int tid = threadIdx.x;
  const float y = ys[(size_t)row * Dn + tid];
  const float mean = blockSum(y, red) * (1.f / 128.f);
  const float d = y - mean;
  const float var = blockSum(d * d, red) * (1.f / 128.f);
  const float v = d * rsqrtf(var + 1e-5f) * g2[n * Dn + tid] + beta2[n * Dn + tid];
  const float o0 = blockSum(v * Wpred[0 * Dn + tid], red);
  const float o1 = blockSum(v * Wpred[1 * Dn + tid], red);
  const float o2 = blockSum(v * Wpred[2 * Dn + tid], red);
  const float o3 = blockSum(v * Wpred[3 * Dn + tid], red);
  if (tid == 0) {
    const float f0 = (o0 + bpred[0]) * alpha[0];
    const float f1 = (o1 + bpred[1]) * alpha[1];
    const float f2 = (o2 + bpred[2]) * alpha[2];
    const float f3 = (o3 + bpred[3]) * alpha[3];
    const float ph0 = ((n / 3) + 0.5f) * (14.f / 3.f);
    const float pw0 = ((n % 3) + 0.5f) * (14.f / 3.f);
    cpar[0] = ph0 + f0;
    cpar[1] = pw0 + f1;
    cpar[2] = (14.f / 3.f) * expf(f2);
    cpar[3] = (14.f / 3.f) * expf(f3);
  }
  __syncthreads();
  if (tid < 14) {
    float s = 0.f;
#pragma unroll
    for (int i = 0; i < 3; ++i) {
      const float rel = (i + 0.5f) / 3.f - 0.5f;
      const float p = cpar[0] + cpar[2] * rel;
      s += fmaxf(1.f - fabsf(p - (float)tid), 0.f);
    }
    khs[(size_t)row * 14 + tid] = s;
  } else if (tid < 28) {
    const int H = tid - 14;
    float s = 0.f;
#pragma unroll
    for (int i = 0; i < 3; ++i) {
      const float rel = (i + 0.5f) / 3.f - 0.5f;
      const float p = cpar[1] + cpar[3] * rel;
      s += fmaxf(1.f - fabsf(p - (float)H), 0.f);
    }
    kws[(size_t)row * 14 + H] = s;
  }
}

// ---------------- transpose W_kp1 [512,196] -> [196,512]
__global__ __launch_bounds__(256) void k_wkp1t(const float* __restrict__ Wkp1,
                                               float* __restrict__ wkT) {
  const int hw = blockIdx.x, c = threadIdx.x;
  wkT[(size_t)hw * Cn + c] = Wkp1[(size_t)c * HWn + hw];
  wkT[(size_t)hw * Cn + c + 256] = Wkp1[(size_t)(c + 256) * HWn + hw];
}

// ---------------- nodes = samp + kern2d @ W_kp1^T + b_kp1 (fp32 + bf16 out)
__global__ __launch_bounds__(256) void k_nodes(const float* __restrict__ feat,
                                               const float* __restrict__ wkT,
                                               const float* __restrict__ khs,
                                               const float* __restrict__ kws,
                                               const float* __restrict__ bkp1,
                                               float* __restrict__ nodes,
                                               u16* __restrict__ nodesb) {
  __shared__ float kh[NN][14], kw[NN][14];
  const int bt = blockIdx.x, tid = threadIdx.x;
  if (tid < NN * 14) {
    kh[tid / 14][tid % 14] = khs[(size_t)bt * NN * 14 + tid];
    kw[tid / 14][tid % 14] = kws[(size_t)bt * NN * 14 + tid];
  }
  __syncthreads();
  float a0[NN] = {}, a1[NN] = {};
  const float* fb = feat + (size_t)bt * HWn * Cn;
  for (int hw = 0; hw < HWn; ++hw) {
    const int Hh = hw / 14, Ll = hw % 14;
    const float f0 = fb[(size_t)hw * Cn + tid] * (1.f / 9.f) + wkT[(size_t)hw * Cn + tid];
    const float f1 = fb[(size_t)hw * Cn + tid + 256] * (1.f / 9.f) + wkT[(size_t)hw * Cn + tid + 256];
#pragma unroll
    for (int n = 0; n < NN; ++n) {
      const float w = kh[n][Hh] * kw[n][Ll];
      a0[n] += w * f0; a1[n] += w * f1;
    }
  }
#pragma unroll
  for (int n = 0; n < NN; ++n) {
    const float v0 = a0[n] + bkp1[tid];
    const float v1 = a1[n] + bkp1[tid + 256];
    nodes[((size_t)bt * NN + n) * Cn + tid] = v0;
    nodes[((size_t)bt * NN + n) * Cn + tid + 256] = v1;
    nodesb[((size_t)bt * NN + n) * Cn + tid] = f2bf(v0);
    nodesb[((size_t)bt * NN + n) * Cn + tid + 256] = f2bf(v1);
  }
}

// ---------------- per-(b,t) 9x9 graph attention (bf16 agg out)
__global__ __launch_bounds__(256) void k_att(const float* __restrict__ q,
                                             const float* __restrict__ k,
                                             const float* __restrict__ v,
                                             u16* __restrict__ aggb) {
  __shared__ __align__(16) float qs[NN][Cn];
  __shared__ __align__(16) float ks[NN][Cn];
  __shared__ __align__(16) float vs[NN][Cn];
  __shared__ float s[NN][NN];
  const int bt = blockIdx.x, tid = threadIdx.x;
  const size_t base = (size_t)bt * NN * Cn;
  for (int idx = tid; idx < NN * Cn; idx += 256) {
    qs[idx / Cn][idx % Cn] = q[base + idx];
    ks[idx / Cn][idx % Cn] = k[base + idx];
    vs[idx / Cn][idx % Cn] = v[base + idx];
  }
  __syncthreads();
  if (tid < NN * NN) {
    const int i = tid / NN, j = tid % NN;
    float acc = 0.f;
    for (int c = 0; c < Cn; c += 4) {
      const float4 qa = *(const float4*)&qs[i][c];
      const float4 kb = *(const float4*)&ks[j][c];
      acc += qa.x * kb.x + qa.y * kb.y + qa.z * kb.z + qa.w * kb.w;
    }
    s[i][j] = acc * 0.044194173824159216f;  // 1/sqrt(512)
  }
  __syncthreads();
  if (tid < NN) {
    float mx = -3.4e38f;
#pragma unroll
    for (int j = 0; j < NN; ++j) mx = fmaxf(mx, s[tid][j]);
    float sum = 0.f;
#pragma unroll
    for (int j = 0; j < NN; ++j) { const float e = expf(s[tid][j] - mx); s[tid][j] = e; sum += e; }
    const float inv = 1.f / sum;
#pragma unroll
    for (int j = 0; j < NN; ++j) s[tid][j] *= inv;
  }
  __syncthreads();
  for (int c = tid; c < Cn; c += 256) {
#pragma unroll
    for (int i = 0; i < NN; ++i) {
      float acc = 0.f;
#pragma unroll
      for (int j = 0; j < NN; ++j) acc += s[i][j] * vs[j][c];
      aggb[((size_t)bt * NN + i) * Cn + c] = f2bf(acc);
    }
  }
}

// ---------------- GRU elementwise update (writes h fp32 + bf16)
template <int T0>
__global__ __launch_bounds__(256) void k_gruupd(const float* __restrict__ gi,
                                                const float* __restrict__ gh,
                                                const float* __restrict__ bghh,
                                                float* __restrict__ hgru,
                                                u16* __restrict__ hb,
                                                float* __restrict__ out_nodes,
                                                int t) {
  const int idx = blockIdx.x * 256 + threadIdx.x;  // 144*512
  const int row = idx >> 9, d = idx & 511;
  const int b = row / NN, n = row % NN;
  const size_t girow = ((size_t)(b * 8 + t) * NN + n) * (3 * Cn);
  const float ir = gi[girow + d], iz = gi[girow + Cn + d], ig = gi[girow + 2 * Cn + d];
  float hr, hz, hg, hp;
  if (T0) {
    hr = bghh[d]; hz = bghh[Cn + d]; hg = bghh[2 * Cn + d]; hp = 0.f;
  } else {
    const size_t gr = (size_t)row * (3 * Cn);
    hr = gh[gr + d]; hz = gh[gr + Cn + d]; hg = gh[gr + 2 * Cn + d];
    hp = hgru[(size_t)row * Cn + d];
  }
  const float rg = sigm(ir + hr);
  const float zg = sigm(iz + hz);
  const float ng = tanhf(ig + rg * hg);
  const float h = (1.f - zg) * ng + zg * hp;
  hgru[(size_t)row * Cn + d] = h;
  hb[(size_t)row * Cn + d] = f2bf(h);
  out_nodes[((size_t)(b * 8 + t) * NN + n) * Cn + d] = h;
}

// ---------------- remap nodes to spatial map: om[r, c] = num/den (bf16 out)
__global__ __launch_bounds__(256) void k_remap(const float* __restrict__ out_nodes,
                                               const float* __restrict__ khs,
                                               const float* __restrict__ kws,
                                               u16* __restrict__ om) {
  __shared__ __align__(16) float on[NN][Cn];
  __shared__ float kh[NN][14], kw[NN][14];
  const int bt = blockIdx.x, tid = threadIdx.x;
  for (int idx = tid; idx < NN * Cn; idx += 256)
    on[idx / Cn][idx % Cn] = out_nodes[(size_t)bt * NN * Cn + idx];
  if (tid < NN * 14) {
    kh[tid / 14][tid % 14] = khs[(size_t)bt * NN * 14 + tid];
    kw[tid / 14][tid % 14] = kws[(size_t)bt * NN * 14 + tid];
  }
  __syncthreads();
  for (int hw = 0; hw < HWn; ++hw) {
    const int Hh = hw / 14, Ll = hw % 14;
    float w[NN];
    float den = 1e-6f;
#pragma unroll
    for (int n = 0; n < NN; ++n) { w[n] = kh[n][Hh] * kw[n][Ll]; den += w[n]; }
    const float inv = 1.f / den;
    float s0 = 0.f, s1 = 0.f;
#pragma unroll
    for (int n = 0; n < NN; ++n) {
      s0 += on[n][tid] * w[n];
      s1 += on[n][tid + 256] * w[n];
    }
    om[((size_t)bt * HWn + hw) * Cn + tid] = f2bf(s0 * inv);
    om[((size_t)bt * HWn + hw) * Cn + tid + 256] = f2bf(s1 * inv);
  }
}

extern "C" void kernel_launch(void* const* d_in, const int* in_sizes, int n_in,
                              void* d_out, int out_size, void* d_ws, size_t ws_size,
                              hipStream_t stream) {
  const float* x      = (const float*)d_in[0];
  const float* W_proj = (const float*)d_in[1];
  const float* b_proj = (const float*)d_in[2];
  const float* W_attn = (const float*)d_in[3];
  const float* W_gf   = (const float*)d_in[4];
  const float* b_gf   = (const float*)d_in[5];
  const float* g1     = (const float*)d_in[6];
  const float* beta1  = (const float*)d_in[7];
  const float* g2     = (const float*)d_in[8];
  const float* beta2  = (const float*)d_in[9];
  const float* W_ih   = (const float*)d_in[10];
  const float* W_hh   = (const float*)d_in[11];
  const float* b_ih   = (const float*)d_in[12];
  const float* b_hh   = (const float*)d_in[13];
  const float* W_pred = (const float*)d_in[14];
  const float* b_pred = (const float*)d_in[15];
  const float* alpha  = (const float*)d_in[16];
  const float* W_kp1  = (const float*)d_in[17];
  const float* b_kp1  = (const float*)d_in[18];
  const float* Wq     = (const float*)d_in[19];
  const float* Wk     = (const float*)d_in[20];
  const float* Wv     = (const float*)d_in[21];
  const float* Wu     = (const float*)d_in[22];
  const float* b_u    = (const float*)d_in[23];
  const float* W_gih  = (const float*)d_in[24];
  const float* W_ghh  = (const float*)d_in[25];
  const float* b_gih  = (const float*)d_in[26];
  const float* b_ghh  = (const float*)d_in[27];
  const float* W_back = (const float*)d_in[28];
  const float* b_back = (const float*)d_in[29];
  float* out = (float*)d_out;

  float* ws = (float*)d_ws;
  // region 0: feat fp32 [25088,512] (later aliased by om bf16)
  float* feat = ws;                       // 12,845,056 floats
  u16* om16 = (u16*)feat;
  // region 1: pool (12,845,056 floats). Fully aliased by xT bf16 until step 1
  // consumes it; then the buffers below live here.
  float* pool = ws + 12845056;
  u16* xT = (u16*)pool;
  size_t off = 0;
  float* attw      = pool + off; off += (size_t)BTn * NN * HWn;   // 225,792
  float* gf        = pool + off; off += (size_t)BTn * NN * Cn;    // 589,824
  u16*   gf2b      = (u16*)(pool + off); off += (size_t)BTn * NN * Dn;  // slot reuse
  float* xW        = pool + off; off += (size_t)BTn * NN * 512;
  float* ys        = pool + off; off += (size_t)BTn * NN * Dn;
  float* khs       = pool + off; off += (size_t)BTn * NN * 14;
  float* kws       = pool + off; off += (size_t)BTn * NN * 14;
  float* nodes     = pool + off; off += (size_t)BTn * NN * Cn;
  float* qb        = pool + off; off += (size_t)BTn * NN * Cn;
  float* kb        = pool + off; off += (size_t)BTn * NN * Cn;
  float* vb        = pool + off; off += (size_t)BTn * NN * Cn;
  float* gi        = pool + off; off += (size_t)BTn * NN * 3 * Cn;
  float* hgru      = pool + off; off += (size_t)144 * Cn;
  float* gh        = pool + off; off += (size_t)144 * 3 * Cn;
  float* wkT       = pool + off; off += (size_t)HWn * Cn;
  float* out_nodes = pool + off; off += (size_t)BTn * NN * Cn;
  // bf16 buffers in pool tail (written only after xT is dead)
  u16* midw    = (u16*)(pool + off); off += 1343488;  // 2,686,976 u16 mid weights
  u16* nodesb  = (u16*)(pool + off); off += 294912;
  u16* nd2b    = (u16*)(pool + off); off += 294912;
  u16* aggb16  = (u16*)(pool + off); off += 294912;
  u16* hb      = (u16*)(pool + off); off += 36864;
  u16* Wqb   = midw;
  u16* Wkb   = midw + 262144;
  u16* Wvb   = midw + 524288;
  u16* Wub   = midw + 786432;
  u16* Wgihb = midw + 1048576;
  u16* Wghhb = midw + 1835008;
  u16* Wihb  = midw + 2621440;
  // region 2: proj/back bf16 weights
  u16* Wpb = (u16*)(ws + 25690112);       // 524,288 u16
  u16* Wbb = (u16*)(ws + 25690112 + 262144);

  // 0. weight casts + x transpose/cast
  k_cast<<<512, 256, 0, stream>>>(W_proj, Wpb, 524288);
  k_cast<<<512, 256, 0, stream>>>(W_back, Wbb, 524288);
  k_xt<<<dim3(128, 16), 256, 0, stream>>>(x, xT);
  // 1. backbone projection (bf16 MFMA)
  k_mm128<0><<<dim3(196, 4), 256, 0, stream>>>(xT, Wpb, b_proj, nullptr, feat, 25088, 512, 1024);
  // 1b. mid-weight casts (xT now dead; midw aliases it)
  k_castall<<<2624, 256, 0, stream>>>(Wq, Wk, Wv, Wu, W_gih, W_ghh, W_ih, midw);
  // 2. attention pooling weights
  k_attnpool<<<BTn, 256, 0, stream>>>(feat, W_attn, attw);
  // 3. gf = attw-weighted pooling of feat
  k_gf<<<BTn, 256, 0, stream>>>(feat, attw, gf);
  // 4. gf2b = bf16(LN(gf @ W_gf^T + b_gf))
  k_gfln<<<BTn * NN, 128, 0, stream>>>(gf, W_gf, b_gf, g1, beta1, gf2b);
  // 5. LSTM input GEMM (bf16 MFMA)
  k_mm128<0><<<dim3(9, 4), 256, 0, stream>>>(gf2b, Wihb, b_ih, nullptr, xW, 1152, 512, 128);
  // 6. LSTM recurrence
  k_lstm<<<144, 256, 0, stream>>>(xW, W_hh, b_hh, ys);
  // 7. offsets -> sampling kernels
  k_off<<<BTn * NN, 128, 0, stream>>>(ys, g2, beta2, W_pred, b_pred, alpha, khs, kws);
  // 8. transpose W_kp1
  k_wkp1t<<<HWn, 256, 0, stream>>>(W_kp1, wkT);
  // 9. nodes = crop-pool + kernel-location embedding (fp32 + bf16)
  k_nodes<<<BTn, 256, 0, stream>>>(feat, wkT, khs, kws, b_kp1, nodes, nodesb);
  // 10. q/k/v projections (bf16 MFMA)
  k_mm128<0><<<dim3(9, 4), 256, 0, stream>>>(nodesb, Wqb, nullptr, nullptr, qb, 1152, 512, 512);
  k_mm128<0><<<dim3(9, 4), 256, 0, stream>>>(nodesb, Wkb, nullptr, nullptr, kb, 1152, 512, 512);
  k_mm128<0><<<dim3(9, 4), 256, 0, stream>>>(nodesb, Wvb, nullptr, nullptr, vb, 1152, 512, 512);
  // 11. 9x9 graph attention (bf16 agg out)
  k_att<<<BTn, 256, 0, stream>>>(qb, kb, vb, aggb16);
  // 12. nd2b = bf16(nodes + relu(agg @ Wu^T + b_u))
  k_mm128<3><<<dim3(9, 4), 256, 0, stream>>>(aggb16, Wub, b_u, nodes, (float*)nd2b, 1152, 512, 512);
  // 13. GRU input GEMM (bf16 MFMA)
  k_mm128<0><<<dim3(9, 12), 256, 0, stream>>>(nd2b, Wgihb, b_gih, nullptr, gi, 1152, 1536, 512);
  // 14. GRU recurrence: per-step hidden GEMM (bf16 MFMA) + update
  for (int t = 0; t < 8; ++t) {
    if (t > 0)
      k_mm128<0><<<dim3(2, 12), 256, 0, stream>>>(hb, Wghhb, b_ghh, nullptr, gh, 144, 1536, 512);
    if (t == 0)
      k_gruupd<1><<<288, 256, 0, stream>>>(gi, gh, b_ghh, hgru, hb, out_nodes, t);
    else
      k_gruupd<0><<<288, 256, 0, stream>>>(gi, gh, b_ghh, hgru, hb, out_nodes, t);
  }
  // 15. remap node states to spatial map (bf16 om aliases feat region)
  k_remap<<<BTn, 256, 0, stream>>>(out_nodes, khs, kws, om16);
  // 16. project back + residual (bf16 MFMA, transposed coalesced epilogue)
  k_mm128<1><<<dim3(196, 8), 256, 0, stream>>>(om16, Wbb, b_back, x, out, 25088, 1024, 512);
}

// Round 4
// 1230.276 us; speedup vs baseline: 1.1634x; 1.1634x over previous
//
#include <hip/hip_runtime.h>

typedef unsigned short u16;
typedef __attribute__((ext_vector_type(8))) u16 b16x8;
typedef __attribute__((ext_vector_type(4))) float f32x4;

static constexpr int HWn = 196;   // 14*14
static constexpr int NN  = 9;     // nodes
static constexpr int Cn  = 512;   // node dim
static constexpr int CBn = 1024;  // backbone dim
static constexpr int Dn  = 128;   // lstm dim
static constexpr int BTn = 128;   // B*T

__device__ __forceinline__ float sigm(float x) { return 1.f / (1.f + expf(-x)); }

__device__ __forceinline__ u16 f2bf(float f) {
  unsigned int u = __builtin_bit_cast(unsigned int, f);
  u = (u + 0x7fff + ((u >> 16) & 1)) >> 16;  // RNE
  return (u16)u;
}
__device__ __forceinline__ float bfhi(unsigned int u) {  // high bf16 -> f32
  return __builtin_bit_cast(float, u & 0xffff0000u);
}
__device__ __forceinline__ float bflo(unsigned int u) {  // low bf16 -> f32
  return __builtin_bit_cast(float, u << 16);
}

__device__ __forceinline__ float waveSum(float v) {
#pragma unroll
  for (int o = 32; o > 0; o >>= 1) v += __shfl_down(v, o, 64);
  return v;
}
__device__ __forceinline__ float waveMax(float v) {
#pragma unroll
  for (int o = 32; o > 0; o >>= 1) v = fmaxf(v, __shfl_down(v, o, 64));
  return v;
}
__device__ __forceinline__ float blockSum(float v, float* red) {
  const int lane = threadIdx.x & 63, wid = threadIdx.x >> 6;
  const int nw = blockDim.x >> 6;
  v = waveSum(v);
  __syncthreads();
  if (lane == 0) red[wid] = v;
  __syncthreads();
  float r = 0.f;
  for (int i = 0; i < nw; ++i) r += red[i];
  return r;
}
__device__ __forceinline__ float blockMax(float v, float* red) {
  const int lane = threadIdx.x & 63, wid = threadIdx.x >> 6;
  const int nw = blockDim.x >> 6;
  v = waveMax(v);
  __syncthreads();
  if (lane == 0) red[wid] = v;
  __syncthreads();
  float r = -3.4e38f;
  for (int i = 0; i < nw; ++i) r = fmaxf(r, red[i]);
  return r;
}

// ---------------- fp32 -> bf16 cast
__global__ __launch_bounds__(256) void k_cast(const float* __restrict__ in,
                                              u16* __restrict__ out, int n) {
  const int i = (blockIdx.x * 256 + threadIdx.x) * 4;
  if (i < n) {
    const float4 v = *(const float4*)&in[i];
    out[i + 0] = f2bf(v.x); out[i + 1] = f2bf(v.y);
    out[i + 2] = f2bf(v.z); out[i + 3] = f2bf(v.w);
  }
}

// ---------------- batched mid-weight cast: Wq|Wk|Wv|Wu|W_gih|W_ih -> contiguous bf16
__global__ __launch_bounds__(256) void k_castall(const float* __restrict__ wq,
                                                 const float* __restrict__ wk,
                                                 const float* __restrict__ wv,
                                                 const float* __restrict__ wu,
                                                 const float* __restrict__ wgih,
                                                 const float* __restrict__ wih,
                                                 u16* __restrict__ dst) {
  const int i = (blockIdx.x * 256 + threadIdx.x) * 4;
  if (i >= 1900544) return;
  const float* src;
  int o = i;
  if (i < 262144) { src = wq; }
  else if (i < 524288)  { src = wk;   o = i - 262144; }
  else if (i < 786432)  { src = wv;   o = i - 524288; }
  else if (i < 1048576) { src = wu;   o = i - 786432; }
  else if (i < 1835008) { src = wgih; o = i - 1048576; }
  else                  { src = wih;  o = i - 1835008; }
  const float4 v = *(const float4*)&src[o];
  dst[i + 0] = f2bf(v.x); dst[i + 1] = f2bf(v.y);
  dst[i + 2] = f2bf(v.z); dst[i + 3] = f2bf(v.w);
}

// ---------------- pack W_ghh [1536][512] -> W3 c-pair-major bf16:
// uintW3[cp*1536 + j] = bf16(W[j][2cp]) | bf16(W[j][2cp+1])<<16
__global__ __launch_bounds__(256) void k_wpack(const float* __restrict__ W,
                                               unsigned int* __restrict__ W3) {
  const int idx = blockIdx.x * 256 + threadIdx.x;  // 256*1536 uints
  if (idx >= 393216) return;
  const int cp = idx / 1536, j = idx % 1536;
  const float lo = W[(size_t)j * 512 + 2 * cp];
  const float hi = W[(size_t)j * 512 + 2 * cp + 1];
  W3[(size_t)cp * 1536 + j] = (unsigned int)f2bf(lo) | ((unsigned int)f2bf(hi) << 16);
}

// ---------------- x[bt][c][hw] fp32 -> xT[(bt,hw)][c] bf16
__global__ __launch_bounds__(256) void k_xt(const float* __restrict__ x,
                                            u16* __restrict__ xT) {
  __shared__ u16 T[64][201];
  const int bt = blockIdx.x, c0 = blockIdx.y * 64, tid = threadIdx.x;
  const float* xb = x + ((size_t)bt * CBn + c0) * HWn;
  for (int idx = tid; idx < 64 * HWn; idx += 256)
    T[idx / HWn][idx % HWn] = f2bf(xb[idx]);
  __syncthreads();
  unsigned int* xTu = (unsigned int*)(xT + ((size_t)bt * HWn) * CBn + c0);
  for (int idx = tid; idx < HWn * 32; idx += 256) {
    const int hw = idx >> 5, j = idx & 31;
    const unsigned int lo = T[2 * j][hw], hi = T[2 * j + 1][hw];
    xTu[(size_t)hw * (CBn / 2) + j] = lo | (hi << 16);
  }
}

// ---------------- bf16 MFMA GEMM, 128x128 tile, C[m,n] = sum_k A[m,k]*B[n,k]
// MODE 0: C fp32 row-major [M,N] (+bias if non-null); LDS epilogue, float4 stores
// MODE 1: out[((m/196)*1024+n)*196 + m%196] = xres + acc + bias[n]; LDS transpose
//         epilogue, float4 stores contiguous along hw
// MODE 3: C16 bf16 row-major = f2bf(resid[m,n] + relu(acc + bias[n])) (small, direct)
template <int MODE>
__global__ __launch_bounds__(256) void k_mm128(const u16* __restrict__ A,
                                               const u16* __restrict__ B,
                                               const float* __restrict__ bias,
                                               const float* __restrict__ xres,
                                               float* __restrict__ C,
                                               const int M, const int N, const int K) {
  __shared__ __align__(16) u16 SM[16896];  // 33792B: staging 32KB; epilogue 2*64*66 f32
  u16* As = SM;
  u16* Bs = SM + 128 * 64;
  const int tid = threadIdx.x;
  const int lane = tid & 63;
  const int w = tid >> 6, wr = w >> 1, wc = w & 1;
  const int m0 = blockIdx.x * 128, n0 = blockIdx.y * 128;

  // staging: 4 chunks (16B) per thread
  int srowA[4], srowB[4], slds[4], sc16[4];
#pragma unroll
  for (int i = 0; i < 4; ++i) {
    const int chunk = i * 256 + tid;
    const int row = chunk >> 3, c16 = chunk & 7;
    srowA[i] = min(m0 + row, M - 1);
    srowB[i] = n0 + row;
    sc16[i] = c16;
    slds[i] = row * 64 + ((c16 ^ (row & 7)) << 3);  // XOR-swizzled 16B slot
  }
  uint4 ar[4], br[4];
#pragma unroll
  for (int i = 0; i < 4; ++i) {
    ar[i] = *(const uint4*)(A + (size_t)srowA[i] * K + sc16[i] * 8);
    br[i] = *(const uint4*)(B + (size_t)srowB[i] * K + sc16[i] * 8);
  }

  // fragment LDS offsets (u16 units), swizzle matched to writes
  int fa[4][2], fb[4][2];
#pragma unroll
  for (int q = 0; q < 4; ++q)
#pragma unroll
    for (int ks = 0; ks < 2; ++ks) {
      const int rowa = wr * 64 + q * 16 + (lane & 15);
      fa[q][ks] = rowa * 64 + (((ks * 4 + (lane >> 4)) ^ (rowa & 7)) << 3);
      const int rowb = wc * 64 + q * 16 + (lane & 15);
      fb[q][ks] = rowb * 64 + (((ks * 4 + (lane >> 4)) ^ (rowb & 7)) << 3);
    }

  f32x4 acc[4][4];
#pragma unroll
  for (int a = 0; a < 4; ++a)
#pragma unroll
    for (int b = 0; b < 4; ++b) acc[a][b] = f32x4{0.f, 0.f, 0.f, 0.f};

  for (int k0 = 0; k0 < K; k0 += 64) {
    __syncthreads();
#pragma unroll
    for (int i = 0; i < 4; ++i) {
      *(uint4*)&As[slds[i]] = ar[i];
      *(uint4*)&Bs[slds[i]] = br[i];
    }
    __syncthreads();
    const int kn = k0 + 64;
    if (kn < K) {
#pragma unroll
      for (int i = 0; i < 4; ++i) {
        ar[i] = *(const uint4*)(A + (size_t)srowA[i] * K + kn + sc16[i] * 8);
        br[i] = *(const uint4*)(B + (size_t)srowB[i] * K + kn + sc16[i] * 8);
      }
    }
    b16x8 af[4][2], bg[4][2];
#pragma unroll
    for (int q = 0; q < 4; ++q)
#pragma unroll
      for (int ks = 0; ks < 2; ++ks) {
        af[q][ks] = *(const b16x8*)&As[fa[q][ks]];
        bg[q][ks] = *(const b16x8*)&Bs[fb[q][ks]];
      }
#pragma unroll
    for (int ks = 0; ks < 2; ++ks)
#pragma unroll
      for (int mi = 0; mi < 4; ++mi)
#pragma unroll
        for (int nj = 0; nj < 4; ++nj) {
          if (MODE == 1)  // swapped operands -> acc holds C^T quadrant
            asm volatile("v_mfma_f32_16x16x32_bf16 %0, %1, %2, %0"
                         : "+v"(acc[mi][nj])
                         : "v"(bg[nj][ks]), "v"(af[mi][ks]));
          else
            asm volatile("v_mfma_f32_16x16x32_bf16 %0, %1, %2, %0"
                         : "+v"(acc[mi][nj])
                         : "v"(af[mi][ks]), "v"(bg[nj][ks]));
        }
  }

  __syncthreads();  // staging LDS is dead; reuse as epilogue buffer
  float* Ct = (float*)SM;  // [2][64][66]

  if (MODE == 0) {
    // acc: m = m0+wr*64+mi*16+(lane>>4)*4+r, n = n0+wc*64+nj*16+(lane&15)
#pragma unroll
    for (int p = 0; p < 2; ++p) {
      if (wr == p) {
#pragma unroll
        for (int mi = 0; mi < 4; ++mi)
#pragma unroll
          for (int nj = 0; nj < 4; ++nj)
#pragma unroll
            for (int r = 0; r < 4; ++r)
              Ct[wc * (64 * 66) + (mi * 16 + (lane >> 4) * 4 + r) * 66 +
                 nj * 16 + (lane & 15)] = acc[mi][nj][r];
      }
      __syncthreads();
      // store 64 m-rows x 128 n, float4: 32 consecutive lanes = 512B contiguous
#pragma unroll
      for (int it = 0; it < 8; ++it) {
        const int f = it * 256 + tid;
        const int mr = f >> 5, nc = (f & 31) * 4;
        const int m = m0 + p * 64 + mr;
        if (m < M) {
          const int half = nc >> 6, nl = nc & 63;
          const float* src = &Ct[half * (64 * 66) + mr * 66 + nl];
          float4 v = make_float4(src[0], src[1], src[2], src[3]);
          if (bias) {
            const float4 bv = *(const float4*)&bias[n0 + nc];
            v.x += bv.x; v.y += bv.y; v.z += bv.z; v.w += bv.w;
          }
          *(float4*)&C[(size_t)m * N + n0 + nc] = v;
        }
      }
      __syncthreads();
    }
  } else if (MODE == 1) {
    // acc (swapped): n = n0+wc*64+nj*16+(lane>>4)*4+r, m = m0+wr*64+mi*16+(lane&15)
#pragma unroll
    for (int p = 0; p < 2; ++p) {
      if (wc == p) {
#pragma unroll
        for (int mi = 0; mi < 4; ++mi)
#pragma unroll
          for (int nj = 0; nj < 4; ++nj)
#pragma unroll
            for (int r = 0; r < 4; ++r)
              Ct[wr * (64 * 66) + (nj * 16 + (lane >> 4) * 4 + r) * 66 +
                 mi * 16 + (lane & 15)] = acc[mi][nj][r];
      }
      __syncthreads();
      // store 64 n-rows x 128 m, float4 contiguous along hw
#pragma unroll
      for (int it = 0; it < 8; ++it) {
        const int f = it * 256 + tid;
        const int nr = f >> 5, mc = (f & 31) * 4;
        const int n = n0 + p * 64 + nr;
        const int m = m0 + mc;
        const int half = mc >> 6, ml = mc & 63;
        const float* src = &Ct[half * (64 * 66) + nr * 66 + ml];
        const float bv = bias[n];
        const int b = m / HWn, hw = m - b * HWn;  // float4 never crosses b bound
        const size_t adr = ((size_t)b * CBn + n) * HWn + hw;
        const float4 xr = *(const float4*)&xres[adr];
        float4 v = make_float4(src[0] + xr.x + bv, src[1] + xr.y + bv,
                               src[2] + xr.z + bv, src[3] + xr.w + bv);
        *(float4*)&C[adr] = v;
      }
      __syncthreads();
    }
  } else {  // MODE 3: small bf16 output, direct stores
#pragma unroll
    for (int nj = 0; nj < 4; ++nj) {
      const int n = n0 + wc * 64 + nj * 16 + (lane & 15);
      const float bv = bias[n];
#pragma unroll
      for (int mi = 0; mi < 4; ++mi) {
#pragma unroll
        for (int r = 0; r < 4; ++r) {
          const int m = m0 + wr * 64 + mi * 16 + (lane >> 4) * 4 + r;
          if (m >= M) continue;
          const float val = xres[(size_t)m * N + n] + fmaxf(acc[mi][nj][r] + bv, 0.f);
          ((u16*)C)[(size_t)m * N + n] = f2bf(val);
        }
      }
    }
  }
}

// ---------------- attention pooling: logits -> softmax over hw -> attw
__global__ __launch_bounds__(256) void k_attnpool(const float* __restrict__ feat,
                                                  const float* __restrict__ Wattn,
                                                  float* __restrict__ attw) {
  __shared__ float S[HWn][65];
  __shared__ float Wa[NN][64];
  __shared__ float L[NN][HWn];
  __shared__ float red[4];
  const int bt = blockIdx.x, tid = threadIdx.x;
  float lacc[NN];
#pragma unroll
  for (int n = 0; n < NN; ++n) lacc[n] = 0.f;
  const float* fb = feat + (size_t)bt * HWn * Cn;
  const int srow = tid >> 4, sc4 = (tid & 15) << 2;
  for (int c0 = 0; c0 < Cn; c0 += 64) {
    for (int rr = srow; rr < HWn; rr += 16) {
      const float4 f = *(const float4*)&fb[(size_t)rr * Cn + c0 + sc4];
      S[rr][sc4] = f.x; S[rr][sc4 + 1] = f.y; S[rr][sc4 + 2] = f.z; S[rr][sc4 + 3] = f.w;
    }
    for (int idx = tid; idx < NN * 64; idx += 256)
      Wa[idx >> 6][idx & 63] = Wattn[(size_t)(idx >> 6) * Cn + c0 + (idx & 63)];
    __syncthreads();
    if (tid < HWn) {
      for (int c = 0; c < 64; ++c) {
        const float s = S[tid][c];
#pragma unroll
        for (int n = 0; n < NN; ++n) lacc[n] += Wa[n][c] * s;
      }
    }
    __syncthreads();
  }
  if (tid < HWn)
#pragma unroll
    for (int n = 0; n < NN; ++n) L[n][tid] = lacc[n];
  __syncthreads();
  for (int n = 0; n < NN; ++n) {
    const float v = (tid < HWn) ? L[n][tid] : -3.4e38f;
    const float mx = blockMax(v, red);
    const float e = (tid < HWn) ? expf(v - mx) : 0.f;
    const float s = blockSum(e, red);
    if (tid < HWn) attw[((size_t)bt * NN + n) * HWn + tid] = e / s;
  }
}

// ---------------- gf[bt,n,c] = sum_hw attw * feat
__global__ __launch_bounds__(256) void k_gf(const float* __restrict__ feat,
                                            const float* __restrict__ attw,
                                            float* __restrict__ gf) {
  __shared__ float aw[NN][HWn];
  const int bt = blockIdx.x, tid = threadIdx.x;
  for (int idx = tid; idx < NN * HWn; idx += 256)
    aw[idx / HWn][idx % HWn] = attw[(size_t)bt * NN * HWn + idx];
  __syncthreads();
  float a0[NN] = {}, a1[NN] = {};
  const float* fb = feat + (size_t)bt * HWn * Cn;
  for (int hw = 0; hw < HWn; ++hw) {
    const float f0 = fb[(size_t)hw * Cn + tid];
    const float f1 = fb[(size_t)hw * Cn + tid + 256];
#pragma unroll
    for (int n = 0; n < NN; ++n) {
      const float w = aw[n][hw];
      a0[n] += w * f0; a1[n] += w * f1;
    }
  }
#pragma unroll
  for (int n = 0; n < NN; ++n) {
    gf[((size_t)bt * NN + n) * Cn + tid] = a0[n];
    gf[((size_t)bt * NN + n) * Cn + tid + 256] = a1[n];
  }
}

// ---------------- gf2b = bf16(LN(gf @ W_gf^T + b_gf) * g1 + beta1)
__global__ __launch_bounds__(128) void k_gfln(const float* __restrict__ gf,
                                              const float* __restrict__ Wgf,
                                              const float* __restrict__ bgf,
                                              const float* __restrict__ g1,
                                              const float* __restrict__ beta1,
                                              u16* __restrict__ gf2b) {
  __shared__ __align__(16) float src[Cn];
  __shared__ float red[4];
  const int row = blockIdx.x;   // bt*9+n
  const int n = row % NN;
  const int tid = threadIdx.x;  // 128
  for (int i = tid; i < Cn; i += 128) src[i] = gf[(size_t)row * Cn + i];
  __syncthreads();
  float acc = bgf[tid];
  const float* wr = Wgf + (size_t)tid * Cn;
  for (int c = 0; c < Cn; c += 4) {
    const float4 w = *(const float4*)&wr[c];
    acc += w.x * src[c] + w.y * src[c + 1] + w.z * src[c + 2] + w.w * src[c + 3];
  }
  const float mean = blockSum(acc, red) * (1.f / 128.f);
  const float d = acc - mean;
  const float var = blockSum(d * d, red) * (1.f / 128.f);
  gf2b[(size_t)row * Dn + tid] =
      f2bf(d * rsqrtf(var + 1e-5f) * g1[n * Dn + tid] + beta1[n * Dn + tid]);
}

// ---------------- LSTM over T=8, one block per (b,n)
__global__ __launch_bounds__(256) void k_lstm(const float* __restrict__ xW,
                                              const float* __restrict__ Whh,
                                              const float* __restrict__ bhh,
                                              float* __restrict__ ys) {
  __shared__ __align__(16) float h[Dn];
  __shared__ float cc[Dn];
  __shared__ float gates[4 * Dn];
  const int blk = blockIdx.x, b = blk / NN, n = blk % NN;
  const int tid = threadIdx.x;
  if (tid < Dn) { h[tid] = 0.f; cc[tid] = 0.f; }
  __syncthreads();
  for (int t = 0; t < 8; ++t) {
    const int bt = b * 8 + t;
    const size_t xrow = ((size_t)bt * NN + n) * (4 * Dn);
#pragma unroll
    for (int gq = 0; gq < 2; ++gq) {
      const int g = tid + gq * 256;
      float acc = xW[xrow + g] + bhh[g];
      const float* wr = Whh + (size_t)g * Dn;
#pragma unroll 8
      for (int d = 0; d < Dn; d += 4) {
        const float4 w = *(const float4*)&wr[d];
        acc += w.x * h[d] + w.y * h[d + 1] + w.z * h[d + 2] + w.w * h[d + 3];
      }
      gates[g] = acc;
    }
    __syncthreads();
    if (tid < Dn) {
      const float ig = sigm(gates[tid]);
      const float fg = sigm(gates[Dn + tid]);
      const float gg = tanhf(gates[2 * Dn + tid]);
      const float og = sigm(gates[3 * Dn + tid]);
      const float cn = fg * cc[tid] + ig * gg;
      const float hn = og * tanhf(cn);
      cc[tid] = cn; h[tid] = hn;
      ys[((size_t)bt * NN + n) * Dn + tid] = hn;
    }
    __syncthreads();
  }
}

// ---------------- offsets -> khs/kws, one block per (bt,n)
__global__ __launch_bounds__(128) void k_off(const float* __restrict__ ys,
                                             const float* __restrict__ g2,
                                             const float* __restrict__ beta2,
                                             const float* __restrict__ Wpred,
                                             const float* __restrict__ bpred,
                                             const float* __restrict__ alpha,
                                             float* __restrict__ khs,
                                             float* __restrict__ kws) {
  __shared__ float red[4];
  __shared__ float cpar[4];  // ch, cw, sh, sw
  const int row = blockIdx.x;  // bt*9+n
  const int n = row % NN;
  const int tid = threadIdx.x;
  const float y = ys[(size_t)row * Dn + tid];
  const float mean = blockSum(y, red) * (1.f / 128.f);
  const float d = y - mean;
  const float var = blockSum(d * d, red) * (1.f / 128.f);
  const float v = d * rsqrtf(var + 1e-5f) * g2[n * Dn + tid] + beta2[n * Dn + tid];
  const float o0 = blockSum(v * Wpred[0 * Dn + tid], red);
  const float o1 = blockSum(v * Wpred[1 * Dn + tid], red);
  const float o2 = blockSum(v * Wpred[2 * Dn + tid], red);
  const float o3 = blockSum(v * Wpred[3 * Dn + tid], red);
  if (tid == 0) {
    const float f0 = (o0 + bpred[0]) * alpha[0];
    const float f1 = (o1 + bpred[1]) * alpha[1];
    const float f2 = (o2 + bpred[2]) * alpha[2];
    const float f3 = (o3 + bpred[3]) * alpha[3];
    const float ph0 = ((n / 3) + 0.5f) * (14.f / 3.f);
    const float pw0 = ((n % 3) + 0.5f) * (14.f / 3.f);
    cpar[0] = ph0 + f0;
    cpar[1] = pw0 + f1;
    cpar[2] = (14.f / 3.f) * expf(f2);
    cpar[3] = (14.f / 3.f) * expf(f3);
  }
  __syncthreads();
  if (tid < 14) {
    float s = 0.f;
#pragma unroll
    for (int i = 0; i < 3; ++i) {
      const float rel = (i + 0.5f) / 3.f - 0.5f;
      const float p = cpar[0] + cpar[2] * rel;
      s += fmaxf(1.f - fabsf(p - (float)tid), 0.f);
    }
    khs[(size_t)row * 14 + tid] = s;
  } else if (tid < 28) {
    const int H = tid - 14;
    float s = 0.f;
#pragma unroll
    for (int i = 0; i < 3; ++i) {
      const float rel = (i + 0.5f) / 3.f - 0.5f;
      const float p = cpar[1] + cpar[3] * rel;
      s += fmaxf(1.f - fabsf(p - (float)H), 0.f);
    }
    kws[(size_t)row * 14 + H] = s;
  }
}

// ---------------- transpose W_kp1 [512,196] -> [196,512]
__global__ __launch_bounds__(256) void k_wkp1t(const float* __restrict__ Wkp1,
                                               float* __restrict__ wkT) {
  const int hw = blockIdx.x, c = threadIdx.x;
  wkT[(size_t)hw * Cn + c] = Wkp1[(size_t)c * HWn + hw];
  wkT[(size_t)hw * Cn + c + 256] = Wkp1[(size_t)(c + 256) * HWn + hw];
}

// ---------------- nodes = samp + kern2d @ W_kp1^T + b_kp1 (fp32 + bf16 out)
__global__ __launch_bounds__(256) void k_nodes(const float* __restrict__ feat,
                                               const float* __restrict__ wkT,
                                               const float* __restrict__ khs,
                                               const float* __restrict__ kws,
                                               const float* __restrict__ bkp1,
                                               float* __restrict__ nodes,
                                               u16* __restrict__ nodesb) {
  __shared__ float kh[NN][14], kw[NN][14];
  const int bt = blockIdx.x, tid = threadIdx.x;
  if (tid < NN * 14) {
    kh[tid / 14][tid % 14] = khs[(size_t)bt * NN * 14 + tid];
    kw[tid / 14][tid % 14] = kws[(size_t)bt * NN * 14 + tid];
  }
  __syncthreads();
  float a0[NN] = {}, a1[NN] = {};
  const float* fb = feat + (size_t)bt * HWn * Cn;
  for (int hw = 0; hw < HWn; ++hw) {
    const int Hh = hw / 14, Ll = hw % 14;
    const float f0 = fb[(size_t)hw * Cn + tid] * (1.f / 9.f) + wkT[(size_t)hw * Cn + tid];
    const float f1 = fb[(size_t)hw * Cn + tid + 256] * (1.f / 9.f) + wkT[(size_t)hw * Cn + tid + 256];
#pragma unroll
    for (int n = 0; n < NN; ++n) {
      const float w = kh[n][Hh] * kw[n][Ll];
      a0[n] += w * f0; a1[n] += w * f1;
    }
  }
#pragma unroll
  for (int n = 0; n < NN; ++n) {
    const float v0 = a0[n] + bkp1[tid];
    const float v1 = a1[n] + bkp1[tid + 256];
    nodes[((size_t)bt * NN + n) * Cn + tid] = v0;
    nodes[((size_t)bt * NN + n) * Cn + tid + 256] = v1;
    nodesb[((size_t)bt * NN + n) * Cn + tid] = f2bf(v0);
    nodesb[((size_t)bt * NN + n) * Cn + tid + 256] = f2bf(v1);
  }
}

// ---------------- per-(b,t) 9x9 graph attention; qkv interleaved [row][1536]
__global__ __launch_bounds__(256) void k_att(const float* __restrict__ qkv,
                                             u16* __restrict__ aggb) {
  __shared__ __align__(16) float qs[NN][Cn];
  __shared__ __align__(16) float ks[NN][Cn];
  __shared__ __align__(16) float vs[NN][Cn];
  __shared__ float s[NN][NN];
  const int bt = blockIdx.x, tid = threadIdx.x;
  const size_t base = (size_t)bt * NN * 1536;
  for (int idx = tid; idx < NN * Cn; idx += 256) {
    const int i = idx / Cn, c = idx % Cn;
    qs[i][c] = qkv[base + (size_t)i * 1536 + c];
    ks[i][c] = qkv[base + (size_t)i * 1536 + 512 + c];
    vs[i][c] = qkv[base + (size_t)i * 1536 + 1024 + c];
  }
  __syncthreads();
  if (tid < NN * NN) {
    const int i = tid / NN, j = tid % NN;
    float acc = 0.f;
    for (int c = 0; c < Cn; c += 4) {
      const float4 qa = *(const float4*)&qs[i][c];
      const float4 kb = *(const float4*)&ks[j][c];
      acc += qa.x * kb.x + qa.y * kb.y + qa.z * kb.z + qa.w * kb.w;
    }
    s[i][j] = acc * 0.044194173824159216f;  // 1/sqrt(512)
  }
  __syncthreads();
  if (tid < NN) {
    float mx = -3.4e38f;
#pragma unroll
    for (int j = 0; j < NN; ++j) mx = fmaxf(mx, s[tid][j]);
    float sum = 0.f;
#pragma unroll
    for (int j = 0; j < NN; ++j) { const float e = expf(s[tid][j] - mx); s[tid][j] = e; sum += e; }
    const float inv = 1.f / sum;
#pragma unroll
    for (int j = 0; j < NN; ++j) s[tid][j] *= inv;
  }
  __syncthreads();
  for (int c = tid; c < Cn; c += 256) {
#pragma unroll
    for (int i = 0; i < NN; ++i) {
      float acc = 0.f;
#pragma unroll
      for (int j = 0; j < NN; ++j) acc += s[i][j] * vs[j][c];
      aggb[((size_t)bt * NN + i) * Cn + c] = f2bf(acc);
    }
  }
}

// ---------------- fused GRU recurrence: one block per (b,n) row, 512 threads
// W3: c-pair-major packed bf16 of W_ghh^T (see k_wpack)
__global__ __launch_bounds__(512) void k_gru(const float* __restrict__ gi,
                                             const unsigned int* __restrict__ W3,
                                             const float* __restrict__ bghh,
                                             float* __restrict__ out_nodes) {
  __shared__ float h[Cn];
  const int row = blockIdx.x, b = row / NN, n = row % NN;
  const int d = threadIdx.x;
  float hcur = 0.f;
  h[d] = 0.f;
  const float br = bghh[d], bz = bghh[Cn + d], bg = bghh[2 * Cn + d];
  __syncthreads();
  for (int t = 0; t < 8; ++t) {
    float ar = br, az = bz, ag = bg;
#pragma unroll 4
    for (int cp = 0; cp < 256; ++cp) {
      const float h0 = h[2 * cp], h1 = h[2 * cp + 1];
      const unsigned int wru = W3[(size_t)cp * 1536 + d];
      const unsigned int wzu = W3[(size_t)cp * 1536 + 512 + d];
      const unsigned int wgu = W3[(size_t)cp * 1536 + 1024 + d];
      ar += bflo(wru) * h0 + bfhi(wru) * h1;
      az += bflo(wzu) * h0 + bfhi(wzu) * h1;
      ag += bflo(wgu) * h0 + bfhi(wgu) * h1;
    }
    const size_t girow = ((size_t)(b * 8 + t) * NN + n) * 1536;
    const float r = sigm(gi[girow + d] + ar);
    const float z = sigm(gi[girow + Cn + d] + az);
    const float g = tanhf(gi[girow + 2 * Cn + d] + r * ag);
    const float hn = (1.f - z) * g + z * hcur;
    __syncthreads();  // all dot-reads of h complete before overwrite
    h[d] = hn; hcur = hn;
    out_nodes[((size_t)(b * 8 + t) * NN + n) * Cn + d] = hn;
    __syncthreads();
  }
}

// ---------------- remap nodes to spatial map: om[r, c] = num/den (bf16 out)
__global__ __launch_bounds__(256) void k_remap(const float* __restrict__ out_nodes,
                                               const float* __restrict__ khs,
                                               const float* __restrict__ kws,
                                               u16* __restrict__ om) {
  __shared__ __align__(16) float on[NN][Cn];
  __shared__ float kh[NN][14], kw[NN][14];
  const int bt = blockIdx.x, tid = threadIdx.x;
  for (int idx = tid; idx < NN * Cn; idx += 256)
    on[idx / Cn][idx % Cn] = out_nodes[(size_t)bt * NN * Cn + idx];
  if (tid < NN * 14) {
    kh[tid / 14][tid % 14] = khs[(size_t)bt * NN * 14 + tid];
    kw[tid / 14][tid % 14] = kws[(size_t)bt * NN * 14 + tid];
  }
  __syncthreads();
  for (int hw = 0; hw < HWn; ++hw) {
    const int Hh = hw / 14, Ll = hw % 14;
    float w[NN];
    float den = 1e-6f;
#pragma unroll
    for (int n = 0; n < NN; ++n) { w[n] = kh[n][Hh] * kw[n][Ll]; den += w[n]; }
    const float inv = 1.f / den;
    float s0 = 0.f, s1 = 0.f;
#pragma unroll
    for (int n = 0; n < NN; ++n) {
      s0 += on[n][tid] * w[n];
      s1 += on[n][tid + 256] * w[n];
    }
    om[((size_t)bt * HWn + hw) * Cn + tid] = f2bf(s0 * inv);
    om[((size_t)bt * HWn + hw) * Cn + tid + 256] = f2bf(s1 * inv);
  }
}

extern "C" void kernel_launch(void* const* d_in, const int* in_sizes, int n_in,
                              void* d_out, int out_size, void* d_ws, size_t ws_size,
                              hipStream_t stream) {
  const float* x      = (const float*)d_in[0];
  const float* W_proj = (const float*)d_in[1];
  const float* b_proj = (const float*)d_in[2];
  const float* W_attn = (const float*)d_in[3];
  const float* W_gf   = (const float*)d_in[4];
  const float* b_gf   = (const float*)d_in[5];
  const float* g1     = (const float*)d_in[6];
  const float* beta1  = (const float*)d_in[7];
  const float* g2     = (const float*)d_in[8];
  const float* beta2  = (const float*)d_in[9];
  const float* W_ih   = (const float*)d_in[10];
  const float* W_hh   = (const float*)d_in[11];
  const float* b_ih   = (const float*)d_in[12];
  const float* b_hh   = (const float*)d_in[13];
  const float* W_pred = (const float*)d_in[14];
  const float* b_pred = (const float*)d_in[15];
  const float* alpha  = (const float*)d_in[16];
  const float* W_kp1  = (const float*)d_in[17];
  const float* b_kp1  = (const float*)d_in[18];
  const float* Wq     = (const float*)d_in[19];
  const float* Wk     = (const float*)d_in[20];
  const float* Wv     = (const float*)d_in[21];
  const float* Wu     = (const float*)d_in[22];
  const float* b_u    = (const float*)d_in[23];
  const float* W_gih  = (const float*)d_in[24];
  const float* W_ghh  = (const float*)d_in[25];
  const float* b_gih  = (const float*)d_in[26];
  const float* b_ghh  = (const float*)d_in[27];
  const float* W_back = (const float*)d_in[28];
  const float* b_back = (const float*)d_in[29];
  float* out = (float*)d_out;

  float* ws = (float*)d_ws;
  // region 0: feat fp32 [25088,512] (later aliased by om bf16)
  float* feat = ws;                       // 12,845,056 floats
  u16* om16 = (u16*)feat;
  // region 1: pool. xT bf16 aliases the WHOLE pool until the feat GEMM consumes
  // it; all buffers below are written only after that.
  float* pool = ws + 12845056;
  u16* xT = (u16*)pool;
  size_t off = 0;
  float* attw      = pool + off; off += (size_t)BTn * NN * HWn;   // 225,792
  float* gf        = pool + off; off += (size_t)BTn * NN * Cn;    // 589,824
  u16*   gf2b      = (u16*)(pool + off); off += (size_t)BTn * NN * Dn / 2 + 64;
  float* xW        = pool + off; off += (size_t)BTn * NN * 512;
  float* ys        = pool + off; off += (size_t)BTn * NN * Dn;
  float* khs       = pool + off; off += (size_t)BTn * NN * 14;
  float* kws       = pool + off; off += (size_t)BTn * NN * 14;
  float* nodes     = pool + off; off += (size_t)BTn * NN * Cn;
  float* qkv       = pool + off; off += (size_t)BTn * NN * 1536;  // 1,769,472
  float* gi        = pool + off; off += (size_t)BTn * NN * 3 * Cn;
  float* wkT       = pool + off; off += (size_t)HWn * Cn;
  float* out_nodes = pool + off; off += (size_t)BTn * NN * Cn;
  u16* midw    = (u16*)(pool + off); off += 950272;  // 1,900,544 u16
  u16* nodesb  = (u16*)(pool + off); off += 147456;
  u16* nd2b    = (u16*)(pool + off); off += 147456;
  u16* aggb16  = (u16*)(pool + off); off += 147456;
  unsigned int* W3 = (unsigned int*)(pool + off); off += 393216;  // packed W_ghh
  u16* Wqkvb = midw;                  // [1536][512] merged q|k|v
  u16* Wub   = midw + 786432;
  u16* Wgihb = midw + 1048576;
  u16* Wihb  = midw + 1835008;
  // region 2: proj/back bf16 weights
  u16* Wpb = (u16*)(ws + 25690112);
  u16* Wbb = (u16*)(ws + 25690112 + 262144);

  // 0. weight casts + x transpose/cast
  k_cast<<<512, 256, 0, stream>>>(W_proj, Wpb, 524288);
  k_cast<<<512, 256, 0, stream>>>(W_back, Wbb, 524288);
  k_xt<<<dim3(128, 16), 256, 0, stream>>>(x, xT);
  // 1. backbone projection (bf16 MFMA, LDS epilogue)
  k_mm128<0><<<dim3(196, 4), 256, 0, stream>>>(xT, Wpb, b_proj, nullptr, feat, 25088, 512, 1024);
  // 1b. mid-weight casts + GRU weight pack (xT now dead)
  k_castall<<<1856, 256, 0, stream>>>(Wq, Wk, Wv, Wu, W_gih, W_ih, midw);
  k_wpack<<<1536, 256, 0, stream>>>(W_ghh, W3);
  // 2-4. attention pooling -> gf -> LN
  k_attnpool<<<BTn, 256, 0, stream>>>(feat, W_attn, attw);
  k_gf<<<BTn, 256, 0, stream>>>(feat, attw, gf);
  k_gfln<<<BTn * NN, 128, 0, stream>>>(gf, W_gf, b_gf, g1, beta1, gf2b);
  // 5-6. LSTM input GEMM + recurrence
  k_mm128<0><<<dim3(9, 4), 256, 0, stream>>>(gf2b, Wihb, b_ih, nullptr, xW, 1152, 512, 128);
  k_lstm<<<144, 256, 0, stream>>>(xW, W_hh, b_hh, ys);
  // 7-9. offsets, W_kp1 transpose, nodes
  k_off<<<BTn * NN, 128, 0, stream>>>(ys, g2, beta2, W_pred, b_pred, alpha, khs, kws);
  k_wkp1t<<<HWn, 256, 0, stream>>>(W_kp1, wkT);
  k_nodes<<<BTn, 256, 0, stream>>>(feat, wkT, khs, kws, b_kp1, nodes, nodesb);
  // 10. merged q|k|v projection (N=1536)
  k_mm128<0><<<dim3(9, 12), 256, 0, stream>>>(nodesb, Wqkvb, nullptr, nullptr, qkv, 1152, 1536, 512);
  // 11. 9x9 graph attention
  k_att<<<BTn, 256, 0, stream>>>(qkv, aggb16);
  // 12. nd2b = bf16(nodes + relu(agg @ Wu^T + b_u))
  k_mm128<3><<<dim3(9, 4), 256, 0, stream>>>(aggb16, Wub, b_u, nodes, (float*)nd2b, 1152, 512, 512);
  // 13. GRU input GEMM
  k_mm128<0><<<dim3(9, 12), 256, 0, stream>>>(nd2b, Wgihb, b_gih, nullptr, gi, 1152, 1536, 512);
  // 14. fused GRU recurrence (all 8 steps, one launch)
  k_gru<<<144, 512, 0, stream>>>(gi, W3, b_ghh, out_nodes);
  // 15. remap node states to spatial map (bf16 om aliases feat region)
  k_remap<<<BTn, 256, 0, stream>>>(out_nodes, khs, kws, om16);
  // 16. project back + residual (bf16 MFMA, LDS-transpose coalesced epilogue)
  k_mm128<1><<<dim3(196, 8), 256, 0, stream>>>(om16, Wbb, b_back, x, out, 25088, 1024, 512);
}

// Round 5
// 1225.349 us; speedup vs baseline: 1.1681x; 1.0040x over previous
//
#include <hip/hip_runtime.h>

typedef unsigned short u16;
typedef __attribute__((ext_vector_type(8))) u16 b16x8;
typedef __attribute__((ext_vector_type(4))) float f32x4;

static constexpr int HWn = 196;   // 14*14
static constexpr int NN  = 9;     // nodes
static constexpr int Cn  = 512;   // node dim
static constexpr int CBn = 1024;  // backbone dim
static constexpr int Dn  = 128;   // lstm dim
static constexpr int BTn = 128;   // B*T

__device__ __forceinline__ float sigm(float x) { return 1.f / (1.f + expf(-x)); }

__device__ __forceinline__ u16 f2bf(float f) {
  unsigned int u = __builtin_bit_cast(unsigned int, f);
  u = (u + 0x7fff + ((u >> 16) & 1)) >> 16;  // RNE
  return (u16)u;
}
__device__ __forceinline__ float bfhi(unsigned int u) {  // high bf16 -> f32
  return __builtin_bit_cast(float, u & 0xffff0000u);
}
__device__ __forceinline__ float bflo(unsigned int u) {  // low bf16 -> f32
  return __builtin_bit_cast(float, u << 16);
}

__device__ __forceinline__ float waveSum(float v) {
#pragma unroll
  for (int o = 32; o > 0; o >>= 1) v += __shfl_down(v, o, 64);
  return v;
}
__device__ __forceinline__ float waveMax(float v) {
#pragma unroll
  for (int o = 32; o > 0; o >>= 1) v = fmaxf(v, __shfl_down(v, o, 64));
  return v;
}
__device__ __forceinline__ float blockSum(float v, float* red) {
  const int lane = threadIdx.x & 63, wid = threadIdx.x >> 6;
  const int nw = blockDim.x >> 6;
  v = waveSum(v);
  __syncthreads();
  if (lane == 0) red[wid] = v;
  __syncthreads();
  float r = 0.f;
  for (int i = 0; i < nw; ++i) r += red[i];
  return r;
}
__device__ __forceinline__ float blockMax(float v, float* red) {
  const int lane = threadIdx.x & 63, wid = threadIdx.x >> 6;
  const int nw = blockDim.x >> 6;
  v = waveMax(v);
  __syncthreads();
  if (lane == 0) red[wid] = v;
  __syncthreads();
  float r = -3.4e38f;
  for (int i = 0; i < nw; ++i) r = fmaxf(r, red[i]);
  return r;
}

// ---------------- fp32 -> bf16 cast
__global__ __launch_bounds__(256) void k_cast(const float* __restrict__ in,
                                              u16* __restrict__ out, int n) {
  const int i = (blockIdx.x * 256 + threadIdx.x) * 4;
  if (i < n) {
    const float4 v = *(const float4*)&in[i];
    out[i + 0] = f2bf(v.x); out[i + 1] = f2bf(v.y);
    out[i + 2] = f2bf(v.z); out[i + 3] = f2bf(v.w);
  }
}

// ---------------- batched mid-weight cast: Wq|Wk|Wv|Wu|W_gih|W_ih -> contiguous bf16
__global__ __launch_bounds__(256) void k_castall(const float* __restrict__ wq,
                                                 const float* __restrict__ wk,
                                                 const float* __restrict__ wv,
                                                 const float* __restrict__ wu,
                                                 const float* __restrict__ wgih,
                                                 const float* __restrict__ wih,
                                                 u16* __restrict__ dst) {
  const int i = (blockIdx.x * 256 + threadIdx.x) * 4;
  if (i >= 1900544) return;
  const float* src;
  int o = i;
  if (i < 262144) { src = wq; }
  else if (i < 524288)  { src = wk;   o = i - 262144; }
  else if (i < 786432)  { src = wv;   o = i - 524288; }
  else if (i < 1048576) { src = wu;   o = i - 786432; }
  else if (i < 1835008) { src = wgih; o = i - 1048576; }
  else                  { src = wih;  o = i - 1835008; }
  const float4 v = *(const float4*)&src[o];
  dst[i + 0] = f2bf(v.x); dst[i + 1] = f2bf(v.y);
  dst[i + 2] = f2bf(v.z); dst[i + 3] = f2bf(v.w);
}

// ---------------- pack W_ghh [1536][512] -> W3 c-pair-major bf16:
// uintW3[cp*1536 + j] = bf16(W[j][2cp]) | bf16(W[j][2cp+1])<<16
__global__ __launch_bounds__(256) void k_wpack(const float* __restrict__ W,
                                               unsigned int* __restrict__ W3) {
  const int idx = blockIdx.x * 256 + threadIdx.x;  // 256*1536 uints
  if (idx >= 393216) return;
  const int cp = idx / 1536, j = idx % 1536;
  const float lo = W[(size_t)j * 512 + 2 * cp];
  const float hi = W[(size_t)j * 512 + 2 * cp + 1];
  W3[(size_t)cp * 1536 + j] = (unsigned int)f2bf(lo) | ((unsigned int)f2bf(hi) << 16);
}

// ---------------- x[bt][c][hw] fp32 -> xT[(bt,hw)][c] bf16
__global__ __launch_bounds__(256) void k_xt(const float* __restrict__ x,
                                            u16* __restrict__ xT) {
  __shared__ u16 T[64][201];
  const int bt = blockIdx.x, c0 = blockIdx.y * 64, tid = threadIdx.x;
  const float* xb = x + ((size_t)bt * CBn + c0) * HWn;
  for (int idx = tid; idx < 64 * HWn; idx += 256)
    T[idx / HWn][idx % HWn] = f2bf(xb[idx]);
  __syncthreads();
  unsigned int* xTu = (unsigned int*)(xT + ((size_t)bt * HWn) * CBn + c0);
  for (int idx = tid; idx < HWn * 32; idx += 256) {
    const int hw = idx >> 5, j = idx & 31;
    const unsigned int lo = T[2 * j][hw], hi = T[2 * j + 1][hw];
    xTu[(size_t)hw * (CBn / 2) + j] = lo | (hi << 16);
  }
}

// ---------------- bf16 MFMA GEMM, 128x128 tile, C[m,n] = sum_k A[m,k]*B[n,k]
// MODE 0: C fp32 row-major [M,N] (+bias if non-null); LDS epilogue, float4 stores
// MODE 1: out[((m/196)*1024+n)*196 + m%196] = xres + acc + bias[n]; LDS transpose
//         epilogue, float4 stores contiguous along hw
// MODE 3: C16 bf16 row-major = f2bf(resid[m,n] + relu(acc + bias[n])) (small, direct)
// __launch_bounds__(256, 2): VGPR cap 256/wave -- accumulators MUST stay resident
// (256-default capped at 84 VGPR and spilled acc to scratch: 5x WRITE_SIZE, 4% MfmaUtil)
template <int MODE>
__global__ __launch_bounds__(256, 2) void k_mm128(const u16* __restrict__ A,
                                                  const u16* __restrict__ B,
                                                  const float* __restrict__ bias,
                                                  const float* __restrict__ xres,
                                                  float* __restrict__ C,
                                                  const int M, const int N, const int K) {
  __shared__ __align__(16) u16 SM[16896];  // 33792B: staging 32KB; epilogue 2*64*66 f32
  u16* As = SM;
  u16* Bs = SM + 128 * 64;
  const int tid = threadIdx.x;
  const int lane = tid & 63;
  const int w = tid >> 6, wr = w >> 1, wc = w & 1;
  const int m0 = blockIdx.x * 128, n0 = blockIdx.y * 128;

  // staging: 4 chunks (16B) per thread
  int srowA[4], srowB[4], slds[4], sc16[4];
#pragma unroll
  for (int i = 0; i < 4; ++i) {
    const int chunk = i * 256 + tid;
    const int row = chunk >> 3, c16 = chunk & 7;
    srowA[i] = min(m0 + row, M - 1);
    srowB[i] = n0 + row;
    sc16[i] = c16;
    slds[i] = row * 64 + ((c16 ^ (row & 7)) << 3);  // XOR-swizzled 16B slot
  }
  uint4 ar[4], br[4];
#pragma unroll
  for (int i = 0; i < 4; ++i) {
    ar[i] = *(const uint4*)(A + (size_t)srowA[i] * K + sc16[i] * 8);
    br[i] = *(const uint4*)(B + (size_t)srowB[i] * K + sc16[i] * 8);
  }

  // fragment LDS offsets (u16 units), swizzle matched to writes
  int fa[4][2], fb[4][2];
#pragma unroll
  for (int q = 0; q < 4; ++q)
#pragma unroll
    for (int ks = 0; ks < 2; ++ks) {
      const int rowa = wr * 64 + q * 16 + (lane & 15);
      fa[q][ks] = rowa * 64 + (((ks * 4 + (lane >> 4)) ^ (rowa & 7)) << 3);
      const int rowb = wc * 64 + q * 16 + (lane & 15);
      fb[q][ks] = rowb * 64 + (((ks * 4 + (lane >> 4)) ^ (rowb & 7)) << 3);
    }

  f32x4 acc[4][4];
#pragma unroll
  for (int a = 0; a < 4; ++a)
#pragma unroll
    for (int b = 0; b < 4; ++b) acc[a][b] = f32x4{0.f, 0.f, 0.f, 0.f};

  for (int k0 = 0; k0 < K; k0 += 64) {
    __syncthreads();
#pragma unroll
    for (int i = 0; i < 4; ++i) {
      *(uint4*)&As[slds[i]] = ar[i];
      *(uint4*)&Bs[slds[i]] = br[i];
    }
    __syncthreads();
    const int kn = k0 + 64;
    if (kn < K) {
#pragma unroll
      for (int i = 0; i < 4; ++i) {
        ar[i] = *(const uint4*)(A + (size_t)srowA[i] * K + kn + sc16[i] * 8);
        br[i] = *(const uint4*)(B + (size_t)srowB[i] * K + kn + sc16[i] * 8);
      }
    }
    // per-ks-half fragment loads: 8 live b16x8 (32 VGPR) instead of 16
#pragma unroll
    for (int ks = 0; ks < 2; ++ks) {
      b16x8 af[4], bg[4];
#pragma unroll
      for (int q = 0; q < 4; ++q) {
        af[q] = *(const b16x8*)&As[fa[q][ks]];
        bg[q] = *(const b16x8*)&Bs[fb[q][ks]];
      }
#pragma unroll
      for (int mi = 0; mi < 4; ++mi)
#pragma unroll
        for (int nj = 0; nj < 4; ++nj) {
          if (MODE == 1)  // swapped operands -> acc holds C^T quadrant
            asm volatile("v_mfma_f32_16x16x32_bf16 %0, %1, %2, %0"
                         : "+v"(acc[mi][nj])
                         : "v"(bg[nj]), "v"(af[mi]));
          else
            asm volatile("v_mfma_f32_16x16x32_bf16 %0, %1, %2, %0"
                         : "+v"(acc[mi][nj])
                         : "v"(af[mi]), "v"(bg[nj]));
        }
    }
  }

  __syncthreads();  // staging LDS is dead; reuse as epilogue buffer
  float* Ct = (float*)SM;  // [2][64][66]

  if (MODE == 0) {
    // acc: m = m0+wr*64+mi*16+(lane>>4)*4+r, n = n0+wc*64+nj*16+(lane&15)
#pragma unroll
    for (int p = 0; p < 2; ++p) {
      if (wr == p) {
#pragma unroll
        for (int mi = 0; mi < 4; ++mi)
#pragma unroll
          for (int nj = 0; nj < 4; ++nj)
#pragma unroll
            for (int r = 0; r < 4; ++r)
              Ct[wc * (64 * 66) + (mi * 16 + (lane >> 4) * 4 + r) * 66 +
                 nj * 16 + (lane & 15)] = acc[mi][nj][r];
      }
      __syncthreads();
      // store 64 m-rows x 128 n, float4: 32 consecutive lanes = 512B contiguous
#pragma unroll
      for (int it = 0; it < 8; ++it) {
        const int f = it * 256 + tid;
        const int mr = f >> 5, nc = (f & 31) * 4;
        const int m = m0 + p * 64 + mr;
        if (m < M) {
          const int half = nc >> 6, nl = nc & 63;
          const float* src = &Ct[half * (64 * 66) + mr * 66 + nl];
          float4 v = make_float4(src[0], src[1], src[2], src[3]);
          if (bias) {
            const float4 bv = *(const float4*)&bias[n0 + nc];
            v.x += bv.x; v.y += bv.y; v.z += bv.z; v.w += bv.w;
          }
          *(float4*)&C[(size_t)m * N + n0 + nc] = v;
        }
      }
      __syncthreads();
    }
  } else if (MODE == 1) {
    // acc (swapped): n = n0+wc*64+nj*16+(lane>>4)*4+r, m = m0+wr*64+mi*16+(lane&15)
#pragma unroll
    for (int p = 0; p < 2; ++p) {
      if (wc == p) {
#pragma unroll
        for (int mi = 0; mi < 4; ++mi)
#pragma unroll
          for (int nj = 0; nj < 4; ++nj)
#pragma unroll
            for (int r = 0; r < 4; ++r)
              Ct[wr * (64 * 66) + (nj * 16 + (lane >> 4) * 4 + r) * 66 +
                 mi * 16 + (lane & 15)] = acc[mi][nj][r];
      }
      __syncthreads();
      // store 64 n-rows x 128 m, float4 contiguous along hw
#pragma unroll
      for (int it = 0; it < 8; ++it) {
        const int f = it * 256 + tid;
        const int nr = f >> 5, mc = (f & 31) * 4;
        const int n = n0 + p * 64 + nr;
        const int m = m0 + mc;
        const int half = mc >> 6, ml = mc & 63;
        const float* src = &Ct[half * (64 * 66) + nr * 66 + ml];
        const float bv = bias[n];
        const int b = m / HWn, hw = m - b * HWn;  // float4 never crosses b bound
        const size_t adr = ((size_t)b * CBn + n) * HWn + hw;
        const float4 xr = *(const float4*)&xres[adr];
        float4 v = make_float4(src[0] + xr.x + bv, src[1] + xr.y + bv,
                               src[2] + xr.z + bv, src[3] + xr.w + bv);
        *(float4*)&C[adr] = v;
      }
      __syncthreads();
    }
  } else {  // MODE 3: small bf16 output, direct stores
#pragma unroll
    for (int nj = 0; nj < 4; ++nj) {
      const int n = n0 + wc * 64 + nj * 16 + (lane & 15);
      const float bv = bias[n];
#pragma unroll
      for (int mi = 0; mi < 4; ++mi) {
#pragma unroll
        for (int r = 0; r < 4; ++r) {
          const int m = m0 + wr * 64 + mi * 16 + (lane >> 4) * 4 + r;
          if (m >= M) continue;
          const float val = xres[(size_t)m * N + n] + fmaxf(acc[mi][nj][r] + bv, 0.f);
          ((u16*)C)[(size_t)m * N + n] = f2bf(val);
        }
      }
    }
  }
}

// ---------------- attention pooling: logits -> softmax over hw -> attw
__global__ __launch_bounds__(256) void k_attnpool(const float* __restrict__ feat,
                                                  const float* __restrict__ Wattn,
                                                  float* __restrict__ attw) {
  __shared__ float S[HWn][65];
  __shared__ float Wa[NN][64];
  __shared__ float L[NN][HWn];
  __shared__ float red[4];
  const int bt = blockIdx.x, tid = threadIdx.x;
  float lacc[NN];
#pragma unroll
  for (int n = 0; n < NN; ++n) lacc[n] = 0.f;
  const float* fb = feat + (size_t)bt * HWn * Cn;
  const int srow = tid >> 4, sc4 = (tid & 15) << 2;
  for (int c0 = 0; c0 < Cn; c0 += 64) {
    for (int rr = srow; rr < HWn; rr += 16) {
      const float4 f = *(const float4*)&fb[(size_t)rr * Cn + c0 + sc4];
      S[rr][sc4] = f.x; S[rr][sc4 + 1] = f.y; S[rr][sc4 + 2] = f.z; S[rr][sc4 + 3] = f.w;
    }
    for (int idx = tid; idx < NN * 64; idx += 256)
      Wa[idx >> 6][idx & 63] = Wattn[(size_t)(idx >> 6) * Cn + c0 + (idx & 63)];
    __syncthreads();
    if (tid < HWn) {
      for (int c = 0; c < 64; ++c) {
        const float s = S[tid][c];
#pragma unroll
        for (int n = 0; n < NN; ++n) lacc[n] += Wa[n][c] * s;
      }
    }
    __syncthreads();
  }
  if (tid < HWn)
#pragma unroll
    for (int n = 0; n < NN; ++n) L[n][tid] = lacc[n];
  __syncthreads();
  for (int n = 0; n < NN; ++n) {
    const float v = (tid < HWn) ? L[n][tid] : -3.4e38f;
    const float mx = blockMax(v, red);
    const float e = (tid < HWn) ? expf(v - mx) : 0.f;
    const float s = blockSum(e, red);
    if (tid < HWn) attw[((size_t)bt * NN + n) * HWn + tid] = e / s;
  }
}

// ---------------- gf[bt,n,c] = sum_hw attw * feat
__global__ __launch_bounds__(256) void k_gf(const float* __restrict__ feat,
                                            const float* __restrict__ attw,
                                            float* __restrict__ gf) {
  __shared__ float aw[NN][HWn];
  const int bt = blockIdx.x, tid = threadIdx.x;
  for (int idx = tid; idx < NN * HWn; idx += 256)
    aw[idx / HWn][idx % HWn] = attw[(size_t)bt * NN * HWn + idx];
  __syncthreads();
  float a0[NN] = {}, a1[NN] = {};
  const float* fb = feat + (size_t)bt * HWn * Cn;
  for (int hw = 0; hw < HWn; ++hw) {
    const float f0 = fb[(size_t)hw * Cn + tid];
    const float f1 = fb[(size_t)hw * Cn + tid + 256];
#pragma unroll
    for (int n = 0; n < NN; ++n) {
      const float w = aw[n][hw];
      a0[n] += w * f0; a1[n] += w * f1;
    }
  }
#pragma unroll
  for (int n = 0; n < NN; ++n) {
    gf[((size_t)bt * NN + n) * Cn + tid] = a0[n];
    gf[((size_t)bt * NN + n) * Cn + tid + 256] = a1[n];
  }
}

// ---------------- gf2b = bf16(LN(gf @ W_gf^T + b_gf) * g1 + beta1)
__global__ __launch_bounds__(128) void k_gfln(const float* __restrict__ gf,
                                              const float* __restrict__ Wgf,
                                              const float* __restrict__ bgf,
                                              const float* __restrict__ g1,
                                              const float* __restrict__ beta1,
                                              u16* __restrict__ gf2b) {
  __shared__ __align__(16) float src[Cn];
  __shared__ float red[4];
  const int row = blockIdx.x;   // bt*9+n
  const int n = row % NN;
  const int tid = threadIdx.x;  // 128
  for (int i = tid; i < Cn; i += 128) src[i] = gf[(size_t)row * Cn + i];
  __syncthreads();
  float acc = bgf[tid];
  const float* wr = Wgf + (size_t)tid * Cn;
  for (int c = 0; c < Cn; c += 4) {
    const float4 w = *(const float4*)&wr[c];
    acc += w.x * src[c] + w.y * src[c + 1] + w.z * src[c + 2] + w.w * src[c + 3];
  }
  const float mean = blockSum(acc, red) * (1.f / 128.f);
  const float d = acc - mean;
  const float var = blockSum(d * d, red) * (1.f / 128.f);
  gf2b[(size_t)row * Dn + tid] =
      f2bf(d * rsqrtf(var + 1e-5f) * g1[n * Dn + tid] + beta1[n * Dn + tid]);
}

// ---------------- LSTM over T=8, one block per (b,n)
__global__ __launch_bounds__(256) void k_lstm(const float* __restrict__ xW,
                                              const float* __restrict__ Whh,
                                              const float* __restrict__ bhh,
                                              float* __restrict__ ys) {
  __shared__ __align__(16) float h[Dn];
  __shared__ float cc[Dn];
  __shared__ float gates[4 * Dn];
  const int blk = blockIdx.x, b = blk / NN, n = blk % NN;
  const int tid = threadIdx.x;
  if (tid < Dn) { h[tid] = 0.f; cc[tid] = 0.f; }
  __syncthreads();
  for (int t = 0; t < 8; ++t) {
    const int bt = b * 8 + t;
    const size_t xrow = ((size_t)bt * NN + n) * (4 * Dn);
#pragma unroll
    for (int gq = 0; gq < 2; ++gq) {
      const int g = tid + gq * 256;
      float acc = xW[xrow + g] + bhh[g];
      const float* wr = Whh + (size_t)g * Dn;
#pragma unroll 8
      for (int d = 0; d < Dn; d += 4) {
        const float4 w = *(const float4*)&wr[d];
        acc += w.x * h[d] + w.y * h[d + 1] + w.z * h[d + 2] + w.w * h[d + 3];
      }
      gates[g] = acc;
    }
    __syncthreads();
    if (tid < Dn) {
      const float ig = sigm(gates[tid]);
      const float fg = sigm(gates[Dn + tid]);
      const float gg = tanhf(gates[2 * Dn + tid]);
      const float og = sigm(gates[3 * Dn + tid]);
      const float cn = fg * cc[tid] + ig * gg;
      const float hn = og * tanhf(cn);
      cc[tid] = cn; h[tid] = hn;
      ys[((size_t)bt * NN + n) * Dn + tid] = hn;
    }
    __syncthreads();
  }
}

// ---------------- offsets -> khs/kws, one block per (bt,n)
__global__ __launch_bounds__(128) void k_off(const float* __restrict__ ys,
                                             const float* __restrict__ g2,
                                             const float* __restrict__ beta2,
                                             const float* __restrict__ Wpred,
                                             const float* __restrict__ bpred,
                                             const float* __restrict__ alpha,
                                             float* __restrict__ khs,
                                             float* __restrict__ kws) {
  __shared__ float red[4];
  __shared__ float cpar[4];  // ch, cw, sh, sw
  const int row = blockIdx.x;  // bt*9+n
  const int n = row % NN;
  const int tid = threadIdx.x;
  const float y = ys[(size_t)row * Dn + tid];
  const float mean = blockSum(y, red) * (1.f / 128.f);
  const float d = y - mean;
  const float var = blockSum(d * d, red) * (1.f / 128.f);
  const float v = d * rsqrtf(var + 1e-5f) * g2[n * Dn + tid] + beta2[n * Dn + tid];
  const float o0 = blockSum(v * Wpred[0 * Dn + tid], red);
  const float o1 = blockSum(v * Wpred[1 * Dn + tid], red);
  const float o2 = blockSum(v * Wpred[2 * Dn + tid], red);
  const float o3 = blockSum(v * Wpred[3 * Dn + tid], red);
  if (tid == 0) {
    const float f0 = (o0 + bpred[0]) * alpha[0];
    const float f1 = (o1 + bpred[1]) * alpha[1];
    const float f2 = (o2 + bpred[2]) * alpha[2];
    const float f3 = (o3 + bpred[3]) * alpha[3];
    const float ph0 = ((n / 3) + 0.5f) * (14.f / 3.f);
    const float pw0 = ((n % 3) + 0.5f) * (14.f / 3.f);
    cpar[0] = ph0 + f0;
    cpar[1] = pw0 + f1;
    cpar[2] = (14.f / 3.f) * expf(f2);
    cpar[3] = (14.f / 3.f) * expf(f3);
  }
  __syncthreads();
  if (tid < 14) {
    float s = 0.f;
#pragma unroll
    for (int i = 0; i < 3; ++i) {
      const float rel = (i + 0.5f) / 3.f - 0.5f;
      const float p = cpar[0] + cpar[2] * rel;
      s += fmaxf(1.f - fabsf(p - (float)tid), 0.f);
    }
    khs[(size_t)row * 14 + tid] = s;
  } else if (tid < 28) {
    const int H = tid - 14;
    float s = 0.f;
#pragma unroll
    for (int i = 0; i < 3; ++i) {
      const float rel = (i + 0.5f) / 3.f - 0.5f;
      const float p = cpar[1] + cpar[3] * rel;
      s += fmaxf(1.f - fabsf(p - (float)H), 0.f);
    }
    kws[(size_t)row * 14 + H] = s;
  }
}

// ---------------- transpose W_kp1 [512,196] -> [196,512]
__global__ __launch_bounds__(256) void k_wkp1t(const float* __restrict__ Wkp1,
                                               float* __restrict__ wkT) {
  const int hw = blockIdx.x, c = threadIdx.x;
  wkT[(size_t)hw * Cn + c] = Wkp1[(size_t)c * HWn + hw];
  wkT[(size_t)hw * Cn + c + 256] = Wkp1[(size_t)(c + 256) * HWn + hw];
}

// ---------------- nodes = samp + kern2d @ W_kp1^T + b_kp1 (fp32 + bf16 out)
__global__ __launch_bounds__(256) void k_nodes(const float* __restrict__ feat,
                                               const float* __restrict__ wkT,
                                               const float* __restrict__ khs,
                                               const float* __restrict__ kws,
                                               const float* __restrict__ bkp1,
                                               float* __restrict__ nodes,
                                               u16* __restrict__ nodesb) {
  __shared__ float kh[NN][14], kw[NN][14];
  const int bt = blockIdx.x, tid = threadIdx.x;
  if (tid < NN * 14) {
    kh[tid / 14][tid % 14] = khs[(size_t)bt * NN * 14 + tid];
    kw[tid / 14][tid % 14] = kws[(size_t)bt * NN * 14 + tid];
  }
  __syncthreads();
  float a0[NN] = {}, a1[NN] = {};
  const float* fb = feat + (size_t)bt * HWn * Cn;
  for (int hw = 0; hw < HWn; ++hw) {
    const int Hh = hw / 14, Ll = hw % 14;
    const float f0 = fb[(size_t)hw * Cn + tid] * (1.f / 9.f) + wkT[(size_t)hw * Cn + tid];
    const float f1 = fb[(size_t)hw * Cn + tid + 256] * (1.f / 9.f) + wkT[(size_t)hw * Cn + tid + 256];
#pragma unroll
    for (int n = 0; n < NN; ++n) {
      const float w = kh[n][Hh] * kw[n][Ll];
      a0[n] += w * f0; a1[n] += w * f1;
    }
  }
#pragma unroll
  for (int n = 0; n < NN; ++n) {
    const float v0 = a0[n] + bkp1[tid];
    const float v1 = a1[n] + bkp1[tid + 256];
    nodes[((size_t)bt * NN + n) * Cn + tid] = v0;
    nodes[((size_t)bt * NN + n) * Cn + tid + 256] = v1;
    nodesb[((size_t)bt * NN + n) * Cn + tid] = f2bf(v0);
    nodesb[((size_t)bt * NN + n) * Cn + tid + 256] = f2bf(v1);
  }
}

// ---------------- per-(b,t) 9x9 graph attention; qkv interleaved [row][1536]
__global__ __launch_bounds__(256) void k_att(const float* __restrict__ qkv,
                                             u16* __restrict__ aggb) {
  __shared__ __align__(16) float qs[NN][Cn];
  __shared__ __align__(16) float ks[NN][Cn];
  __shared__ __align__(16) float vs[NN][Cn];
  __shared__ float s[NN][NN];
  const int bt = blockIdx.x, tid = threadIdx.x;
  const size_t base = (size_t)bt * NN * 1536;
  for (int idx = tid; idx < NN * Cn; idx += 256) {
    const int i = idx / Cn, c = idx % Cn;
    qs[i][c] = qkv[base + (size_t)i * 1536 + c];
    ks[i][c] = qkv[base + (size_t)i * 1536 + 512 + c];
    vs[i][c] = qkv[base + (size_t)i * 1536 + 1024 + c];
  }
  __syncthreads();
  if (tid < NN * NN) {
    const int i = tid / NN, j = tid % NN;
    float acc = 0.f;
    for (int c = 0; c < Cn; c += 4) {
      const float4 qa = *(const float4*)&qs[i][c];
      const float4 kb = *(const float4*)&ks[j][c];
      acc += qa.x * kb.x + qa.y * kb.y + qa.z * kb.z + qa.w * kb.w;
    }
    s[i][j] = acc * 0.044194173824159216f;  // 1/sqrt(512)
  }
  __syncthreads();
  if (tid < NN) {
    float mx = -3.4e38f;
#pragma unroll
    for (int j = 0; j < NN; ++j) mx = fmaxf(mx, s[tid][j]);
    float sum = 0.f;
#pragma unroll
    for (int j = 0; j < NN; ++j) { const float e = expf(s[tid][j] - mx); s[tid][j] = e; sum += e; }
    const float inv = 1.f / sum;
#pragma unroll
    for (int j = 0; j < NN; ++j) s[tid][j] *= inv;
  }
  __syncthreads();
  for (int c = tid; c < Cn; c += 256) {
#pragma unroll
    for (int i = 0; i < NN; ++i) {
      float acc = 0.f;
#pragma unroll
      for (int j = 0; j < NN; ++j) acc += s[i][j] * vs[j][c];
      aggb[((size_t)bt * NN + i) * Cn + c] = f2bf(acc);
    }
  }
}

// ---------------- fused GRU recurrence: one block per (b,n) row, 512 threads
// W3: c-pair-major packed bf16 of W_ghh^T (see k_wpack)
__global__ __launch_bounds__(512) void k_gru(const float* __restrict__ gi,
                                             const unsigned int* __restrict__ W3,
                                             const float* __restrict__ bghh,
                                             float* __restrict__ out_nodes) {
  __shared__ float h[Cn];
  const int row = blockIdx.x, b = row / NN, n = row % NN;
  const int d = threadIdx.x;
  float hcur = 0.f;
  h[d] = 0.f;
  const float br = bghh[d], bz = bghh[Cn + d], bg = bghh[2 * Cn + d];
  __syncthreads();
  for (int t = 0; t < 8; ++t) {
    float ar = br, az = bz, ag = bg;
#pragma unroll 4
    for (int cp = 0; cp < 256; ++cp) {
      const float h0 = h[2 * cp], h1 = h[2 * cp + 1];
      const unsigned int wru = W3[(size_t)cp * 1536 + d];
      const unsigned int wzu = W3[(size_t)cp * 1536 + 512 + d];
      const unsigned int wgu = W3[(size_t)cp * 1536 + 1024 + d];
      ar += bflo(wru) * h0 + bfhi(wru) * h1;
      az += bflo(wzu) * h0 + bfhi(wzu) * h1;
      ag += bflo(wgu) * h0 + bfhi(wgu) * h1;
    }
    const size_t girow = ((size_t)(b * 8 + t) * NN + n) * 1536;
    const float r = sigm(gi[girow + d] + ar);
    const float z = sigm(gi[girow + Cn + d] + az);
    const float g = tanhf(gi[girow + 2 * Cn + d] + r * ag);
    const float hn = (1.f - z) * g + z * hcur;
    __syncthreads();  // all dot-reads of h complete before overwrite
    h[d] = hn; hcur = hn;
    out_nodes[((size_t)(b * 8 + t) * NN + n) * Cn + d] = hn;
    __syncthreads();
  }
}

// ---------------- remap nodes to spatial map: om[r, c] = num/den (bf16 out)
__global__ __launch_bounds__(256) void k_remap(const float* __restrict__ out_nodes,
                                               const float* __restrict__ khs,
                                               const float* __restrict__ kws,
                                               u16* __restrict__ om) {
  __shared__ __align__(16) float on[NN][Cn];
  __shared__ float kh[NN][14], kw[NN][14];
  const int bt = blockIdx.x, tid = threadIdx.x;
  for (int idx = tid; idx < NN * Cn; idx += 256)
    on[idx / Cn][idx % Cn] = out_nodes[(size_t)bt * NN * Cn + idx];
  if (tid < NN * 14) {
    kh[tid / 14][tid % 14] = khs[(size_t)bt * NN * 14 + tid];
    kw[tid / 14][tid % 14] = kws[(size_t)bt * NN * 14 + tid];
  }
  __syncthreads();
  for (int hw = 0; hw < HWn; ++hw) {
    const int Hh = hw / 14, Ll = hw % 14;
    float w[NN];
    float den = 1e-6f;
#pragma unroll
    for (int n = 0; n < NN; ++n) { w[n] = kh[n][Hh] * kw[n][Ll]; den += w[n]; }
    const float inv = 1.f / den;
    float s0 = 0.f, s1 = 0.f;
#pragma unroll
    for (int n = 0; n < NN; ++n) {
      s0 += on[n][tid] * w[n];
      s1 += on[n][tid + 256] * w[n];
    }
    om[((size_t)bt * HWn + hw) * Cn + tid] = f2bf(s0 * inv);
    om[((size_t)bt * HWn + hw) * Cn + tid + 256] = f2bf(s1 * inv);
  }
}

extern "C" void kernel_launch(void* const* d_in, const int* in_sizes, int n_in,
                              void* d_out, int out_size, void* d_ws, size_t ws_size,
                              hipStream_t stream) {
  const float* x      = (const float*)d_in[0];
  const float* W_proj = (const float*)d_in[1];
  const float* b_proj = (const float*)d_in[2];
  const float* W_attn = (const float*)d_in[3];
  const float* W_gf   = (const float*)d_in[4];
  const float* b_gf   = (const float*)d_in[5];
  const float* g1     = (const float*)d_in[6];
  const float* beta1  = (const float*)d_in[7];
  const float* g2     = (const float*)d_in[8];
  const float* beta2  = (const float*)d_in[9];
  const float* W_ih   = (const float*)d_in[10];
  const float* W_hh   = (const float*)d_in[11];
  const float* b_ih   = (const float*)d_in[12];
  const float* b_hh   = (const float*)d_in[13];
  const float* W_pred = (const float*)d_in[14];
  const float* b_pred = (const float*)d_in[15];
  const float* alpha  = (const float*)d_in[16];
  const float* W_kp1  = (const float*)d_in[17];
  const float* b_kp1  = (const float*)d_in[18];
  const float* Wq     = (const float*)d_in[19];
  const float* Wk     = (const float*)d_in[20];
  const float* Wv     = (const float*)d_in[21];
  const float* Wu     = (const float*)d_in[22];
  const float* b_u    = (const float*)d_in[23];
  const float* W_gih  = (const float*)d_in[24];
  const float* W_ghh  = (const float*)d_in[25];
  const float* b_gih  = (const float*)d_in[26];
  const float* b_ghh  = (const float*)d_in[27];
  const float* W_back = (const float*)d_in[28];
  const float* b_back = (const float*)d_in[29];
  float* out = (float*)d_out;

  float* ws = (float*)d_ws;
  // region 0: feat fp32 [25088,512] (later aliased by om bf16)
  float* feat = ws;                       // 12,845,056 floats
  u16* om16 = (u16*)feat;
  // region 1: pool. xT bf16 aliases the WHOLE pool until the feat GEMM consumes
  // it; all buffers below are written only after that.
  float* pool = ws + 12845056;
  u16* xT = (u16*)pool;
  size_t off = 0;
  float* attw      = pool + off; off += (size_t)BTn * NN * HWn;   // 225,792
  float* gf        = pool + off; off += (size_t)BTn * NN * Cn;    // 589,824
  u16*   gf2b      = (u16*)(pool + off); off += (size_t)BTn * NN * Dn / 2 + 64;
  float* xW        = pool + off; off += (size_t)BTn * NN * 512;
  float* ys        = pool + off; off += (size_t)BTn * NN * Dn;
  float* khs       = pool + off; off += (size_t)BTn * NN * 14;
  float* kws       = pool + off; off += (size_t)BTn * NN * 14;
  float* nodes     = pool + off; off += (size_t)BTn * NN * Cn;
  float* qkv       = pool + off; off += (size_t)BTn * NN * 1536;  // 1,769,472
  float* gi        = pool + off; off += (size_t)BTn * NN * 3 * Cn;
  float* wkT       = pool + off; off += (size_t)HWn * Cn;
  float* out_nodes = pool + off; off += (size_t)BTn * NN * Cn;
  u16* midw    = (u16*)(pool + off); off += 950272;  // 1,900,544 u16
  u16* nodesb  = (u16*)(pool + off); off += 147456;
  u16* nd2b    = (u16*)(pool + off); off += 147456;
  u16* aggb16  = (u16*)(pool + off); off += 147456;
  unsigned int* W3 = (unsigned int*)(pool + off); off += 393216;  // packed W_ghh
  u16* Wqkvb = midw;                  // [1536][512] merged q|k|v
  u16* Wub   = midw + 786432;
  u16* Wgihb = midw + 1048576;
  u16* Wihb  = midw + 1835008;
  // region 2: proj/back bf16 weights
  u16* Wpb = (u16*)(ws + 25690112);
  u16* Wbb = (u16*)(ws + 25690112 + 262144);

  // 0. weight casts + x transpose/cast
  k_cast<<<512, 256, 0, stream>>>(W_proj, Wpb, 524288);
  k_cast<<<512, 256, 0, stream>>>(W_back, Wbb, 524288);
  k_xt<<<dim3(128, 16), 256, 0, stream>>>(x, xT);
  // 1. backbone projection (bf16 MFMA, LDS epilogue)
  k_mm128<0><<<dim3(196, 4), 256, 0, stream>>>(xT, Wpb, b_proj, nullptr, feat, 25088, 512, 1024);
  // 1b. mid-weight casts + GRU weight pack (xT now dead)
  k_castall<<<1856, 256, 0, stream>>>(Wq, Wk, Wv, Wu, W_gih, W_ih, midw);
  k_wpack<<<1536, 256, 0, stream>>>(W_ghh, W3);
  // 2-4. attention pooling -> gf -> LN
  k_attnpool<<<BTn, 256, 0, stream>>>(feat, W_attn, attw);
  k_gf<<<BTn, 256, 0, stream>>>(feat, attw, gf);
  k_gfln<<<BTn * NN, 128, 0, stream>>>(gf, W_gf, b_gf, g1, beta1, gf2b);
  // 5-6. LSTM input GEMM + recurrence
  k_mm128<0><<<dim3(9, 4), 256, 0, stream>>>(gf2b, Wihb, b_ih, nullptr, xW, 1152, 512, 128);
  k_lstm<<<144, 256, 0, stream>>>(xW, W_hh, b_hh, ys);
  // 7-9. offsets, W_kp1 transpose, nodes
  k_off<<<BTn * NN, 128, 0, stream>>>(ys, g2, beta2, W_pred, b_pred, alpha, khs, kws);
  k_wkp1t<<<HWn, 256, 0, stream>>>(W_kp1, wkT);
  k_nodes<<<BTn, 256, 0, stream>>>(feat, wkT, khs, kws, b_kp1, nodes, nodesb);
  // 10. merged q|k|v projection (N=1536)
  k_mm128<0><<<dim3(9, 12), 256, 0, stream>>>(nodesb, Wqkvb, nullptr, nullptr, qkv, 1152, 1536, 512);
  // 11. 9x9 graph attention
  k_att<<<BTn, 256, 0, stream>>>(qkv, aggb16);
  // 12. nd2b = bf16(nodes + relu(agg @ Wu^T + b_u))
  k_mm128<3><<<dim3(9, 4), 256, 0, stream>>>(aggb16, Wub, b_u, nodes, (float*)nd2b, 1152, 512, 512);
  // 13. GRU input GEMM
  k_mm128<0><<<dim3(9, 12), 256, 0, stream>>>(nd2b, Wgihb, b_gih, nullptr, gi, 1152, 1536, 512);
  // 14. fused GRU recurrence (all 8 steps, one launch)
  k_gru<<<144, 512, 0, stream>>>(gi, W3, b_ghh, out_nodes);
  // 15. remap node states to spatial map (bf16 om aliases feat region)
  k_remap<<<BTn, 256, 0, stream>>>(out_nodes, khs, kws, om16);
  // 16. project back + residual (bf16 MFMA, LDS-transpose coalesced epilogue)
  k_mm128<1><<<dim3(196, 8), 256, 0, stream>>>(om16, Wbb, b_back, x, out, 25088, 1024, 512);
}